// Round 2
// baseline (5120.847 us; speedup 1.0000x reference)
//
#include <hip/hip_runtime.h>
#include <hip/hip_bf16.h>

#define N_NODES 20000
#define N_EDGES 320000

typedef __attribute__((ext_vector_type(8))) short shortx8;
typedef __attribute__((ext_vector_type(4))) float floatx4;
using bf16 = __hip_bfloat16;

// ---------------- graph prep ----------------

__global__ void zero_kernel(int* p, int n) {
  int i = blockIdx.x * 256 + threadIdx.x;
  if (i < n) p[i] = 0;
}

__global__ void deg_kernel(const int* __restrict__ row, const int* __restrict__ col,
                           int* __restrict__ deg, int nE) {
  int e = blockIdx.x * 256 + threadIdx.x;
  if (e >= nE) return;
  int r = row[e], c = col[e];
  if (r != c) atomicAdd(&deg[r], 1);
}

__global__ void dis_kernel(const int* __restrict__ deg, float* __restrict__ dis, int n) {
  int i = blockIdx.x * 256 + threadIdx.x;
  if (i >= n) return;
  int d = deg[i];
  dis[i] = (d > 0) ? (1.0f / sqrtf((float)d)) : 0.0f;
}

// single-block exclusive scan of deg[0..n) -> row_ptr[0..n], copy to cursor
__global__ __launch_bounds__(1024) void scan_kernel(const int* __restrict__ deg,
                                                    int* __restrict__ row_ptr,
                                                    int* __restrict__ cursor, int n) {
  __shared__ int part[1024];
  int t = threadIdx.x;
  int base = t * 20;
  int loc[20];
  int s = 0;
#pragma unroll
  for (int i = 0; i < 20; i++) {
    int idx = base + i;
    int v = (idx < n) ? deg[idx] : 0;
    loc[i] = s;
    s += v;
  }
  part[t] = s;
  __syncthreads();
  for (int offd = 1; offd < 1024; offd <<= 1) {
    int v = (t >= offd) ? part[t - offd] : 0;
    __syncthreads();
    part[t] += v;
    __syncthreads();
  }
  int basev = (t > 0) ? part[t - 1] : 0;
#pragma unroll
  for (int i = 0; i < 20; i++) {
    int idx = base + i;
    if (idx < n) {
      int rp = basev + loc[i];
      row_ptr[idx] = rp;
      cursor[idx] = rp;
    }
  }
  if (t == 1023) row_ptr[n] = part[1023];
}

__global__ void scatter_kernel(const int* __restrict__ row, const int* __restrict__ col,
                               const float* __restrict__ dis, int* __restrict__ cursor,
                               int* __restrict__ col_s, float* __restrict__ w_s, int nE) {
  int e = blockIdx.x * 256 + threadIdx.x;
  if (e >= nE) return;
  int r = row[e], c = col[e];
  if (r == c) return;
  int p = atomicAdd(&cursor[r], 1);
  col_s[p] = c;
  w_s[p] = -dis[r] * dis[c];
}

// ---------------- weight prep: W (K,I,J) fp32 -> Wt[k][j][i] bf16 ----------------

__global__ void wtrans_kernel(const float* __restrict__ W, bf16* __restrict__ Wt,
                              int K_, int I, int J) {
  __shared__ float tile[32][33];
  int jt = blockIdx.x % (J / 32);
  int rest = blockIdx.x / (J / 32);
  int it = rest % (I / 32);
  int k = rest / (I / 32);
  int tx = threadIdx.x, ty = threadIdx.y;
  const float* src = W + (size_t)k * I * J;
  for (int r = ty; r < 32; r += 8)
    tile[r][tx] = src[(size_t)(it * 32 + r) * J + jt * 32 + tx];
  __syncthreads();
  for (int r = ty; r < 32; r += 8) {
    int j = jt * 32 + r;
    Wt[((size_t)k * J + j) * I + it * 32 + tx] = bf16(tile[tx][r]);
  }
}

// ---------------- cast x (fp32, N x 1152 flat) -> bf16 ----------------

__global__ void cast_x_kernel(const float* __restrict__ x, bf16* __restrict__ dst, int n4) {
  int idx = blockIdx.x * 256 + threadIdx.x;
  if (idx >= n4) return;
  int flat = idx * 4;
  float4 v = *(const float4*)(x + flat);
  dst[flat + 0] = bf16(v.x);
  dst[flat + 1] = bf16(v.y);
  dst[flat + 2] = bf16(v.z);
  dst[flat + 3] = bf16(v.w);
}

// ---------------- prop: dst = L~ src, or dst = 2*L~ src - tx0 (tx0 may alias dst) ----
// one block (256 thr) per node; features strided by 256. No __restrict__ on tx0/dst:
// for k>=2 they alias (in-place overwrite of Tx_{k-2}; each block touches only its row).

template <int F>
__global__ __launch_bounds__(256) void prop_kernel(
    const int* __restrict__ row_ptr, const int* __restrict__ col_s,
    const float* __restrict__ w_s, const bf16* __restrict__ src,
    const bf16* tx0, bf16* dst) {
  constexpr int NF = (F + 255) / 256;
  int node = blockIdx.x;
  int t = threadIdx.x;
  int e0 = row_ptr[node], e1 = row_ptr[node + 1];
  float acc[NF];
#pragma unroll
  for (int j = 0; j < NF; j++) acc[j] = 0.0f;
  for (int e = e0; e < e1; e++) {
    int c = col_s[e];
    float w = w_s[e];
    const bf16* srow = src + (size_t)c * F;
#pragma unroll
    for (int j = 0; j < NF; j++) {
      int f = t + j * 256;
      if (f < F) acc[j] += w * (float)srow[f];
    }
  }
  bf16* drow = dst + (size_t)node * F;
  if (tx0) {
    const bf16* t0 = tx0 + (size_t)node * F;
#pragma unroll
    for (int j = 0; j < NF; j++) {
      int f = t + j * 256;
      if (f < F) drow[f] = bf16(2.0f * acc[j] - (float)t0[f]);
    }
  } else {
#pragma unroll
    for (int j = 0; j < NF; j++) {
      int f = t + j * 256;
      if (f < F) drow[f] = bf16(acc[j]);
    }
  }
}

// ---------------- bf16 MFMA GEMM with accumulation modes ----------------
// A: M x Kt bf16 row-major; Bt: Nout x Kt bf16 (B transposed).
// MODE 0 (INIT):  accbuf = A@B + bias          (fp32, stride Nout)
// MODE 1 (ACCUM): accbuf += A@B
// MODE 2 (FINAL_BF16): dst = relu(accbuf + A@B) cast bf16, stride dstLd
// MODE 3 (FINAL_F32):  dst = relu(accbuf + A@B) fp32, stride Nout

template <int MODE>
__global__ __launch_bounds__(256) void gemm_kernel(
    const bf16* __restrict__ A, const bf16* __restrict__ Bt,
    const float* __restrict__ bias, float* __restrict__ accbuf,
    void* __restrict__ dst, int M, int Nout, int Kt, int dstLd) {
  __shared__ bf16 As[128][40];
  __shared__ bf16 Bs[128][40];
  int nb = (Nout + 127) >> 7;
  int bm = blockIdx.x / nb;
  int bn = blockIdx.x - bm * nb;
  int m0 = bm << 7, n0 = bn << 7;
  int t = threadIdx.x;
  int lane = t & 63;
  int wave = t >> 6;
  int wm = wave & 1, wn = wave >> 1;
  int l16 = lane & 15;
  int k8 = (lane >> 4) << 3;
  floatx4 acc[4][4] = {};
  int rr0 = t >> 2;
  int cc = (t & 3) << 3;  // element offset within 32-wide K slab
  for (int kt = 0; kt < Kt; kt += 32) {
#pragma unroll
    for (int p = 0; p < 2; p++) {
      int rr = rr0 + p * 64;
      uint4 av = make_uint4(0, 0, 0, 0);
      int ga = m0 + rr;
      if (ga < M) av = *(const uint4*)(A + (size_t)ga * Kt + kt + cc);
      *(uint4*)(&As[rr][cc]) = av;
      uint4 bv = make_uint4(0, 0, 0, 0);
      int gb = n0 + rr;
      if (gb < Nout) bv = *(const uint4*)(Bt + (size_t)gb * Kt + kt + cc);
      *(uint4*)(&Bs[rr][cc]) = bv;
    }
    __syncthreads();
    shortx8 af[4], bfr[4];
#pragma unroll
    for (int i = 0; i < 4; i++)
      af[i] = *(const shortx8*)(&As[(wm << 6) + (i << 4) + l16][k8]);
#pragma unroll
    for (int j = 0; j < 4; j++)
      bfr[j] = *(const shortx8*)(&Bs[(wn << 6) + (j << 4) + l16][k8]);
#pragma unroll
    for (int i = 0; i < 4; i++)
#pragma unroll
      for (int j = 0; j < 4; j++)
        acc[i][j] = __builtin_amdgcn_mfma_f32_16x16x32_bf16(af[i], bfr[j], acc[i][j], 0, 0, 0);
    __syncthreads();
  }
  // epilogue: C/D layout col = lane&15, row = (lane>>4)*4 + reg
  int lq = lane >> 4;
#pragma unroll
  for (int j = 0; j < 4; j++) {
    int colg = n0 + (wn << 6) + (j << 4) + l16;
    if (colg >= Nout) continue;
    float bv = (MODE == 0) ? bias[colg] : 0.0f;
#pragma unroll
    for (int i = 0; i < 4; i++) {
      int rowb = m0 + (wm << 6) + (i << 4) + (lq << 2);
#pragma unroll
      for (int q = 0; q < 4; q++) {
        int rowg = rowb + q;
        if (rowg >= M) continue;
        float v = acc[i][j][q];
        size_t aidx = (size_t)rowg * Nout + colg;
        if constexpr (MODE == 0) {
          accbuf[aidx] = v + bv;
        } else if constexpr (MODE == 1) {
          accbuf[aidx] += v;
        } else if constexpr (MODE == 2) {
          float s = fmaxf(accbuf[aidx] + v, 0.0f);
          ((bf16*)dst)[(size_t)rowg * dstLd + colg] = bf16(s);
        } else {
          float s = fmaxf(accbuf[aidx] + v, 0.0f);
          ((float*)dst)[(size_t)rowg * Nout + colg] = s;
        }
      }
    }
  }
}

// ---------------- host launch ----------------

extern "C" void kernel_launch(void* const* d_in, const int* in_sizes, int n_in,
                              void* d_out, int out_size, void* d_ws, size_t ws_size,
                              hipStream_t stream) {
  const float* x = (const float*)d_in[0];
  const int* row = (const int*)d_in[1];
  const int* col = (const int*)d_in[2];
  const float* W1 = (const float*)d_in[3];
  const float* b1 = (const float*)d_in[4];
  const float* W2 = (const float*)d_in[5];
  const float* b2 = (const float*)d_in[6];
  const float* W3 = (const float*)d_in[7];
  const float* b3 = (const float*)d_in[8];

  char* ws = (char*)d_ws;
  size_t off = 0;
  auto alloc = [&](size_t bytes) -> void* {
    void* p = ws + off;
    off += (bytes + 255) & ~(size_t)255;
    return p;
  };

  // ~194 MiB total
  bf16* Wt = (bf16*)alloc((size_t)6 * 1152 * 1152 * 2);  // reused per layer
  int* deg = (int*)alloc(N_NODES * 4);
  float* dis = (float*)alloc(N_NODES * 4);
  int* row_ptr = (int*)alloc((N_NODES + 1) * 4);
  int* cursor = (int*)alloc(N_NODES * 4);
  int* col_s = (int*)alloc(N_EDGES * 4);
  float* w_s = (float*)alloc(N_EDGES * 4);
  bf16* TxP = (bf16*)alloc((size_t)N_NODES * 1152 * 2);
  bf16* TxQ = (bf16*)alloc((size_t)N_NODES * 1152 * 2);
  float* accb = (float*)alloc((size_t)N_NODES * 1152 * 4);
  if (off > ws_size) return;  // workspace too small -> validation will fail loudly

  // graph prep
  zero_kernel<<<(N_NODES + 255) / 256, 256, 0, stream>>>(deg, N_NODES);
  deg_kernel<<<(N_EDGES + 255) / 256, 256, 0, stream>>>(row, col, deg, N_EDGES);
  dis_kernel<<<(N_NODES + 255) / 256, 256, 0, stream>>>(deg, dis, N_NODES);
  scan_kernel<<<1, 1024, 0, stream>>>(deg, row_ptr, cursor, N_NODES);
  scatter_kernel<<<(N_EDGES + 255) / 256, 256, 0, stream>>>(row, col, dis, cursor,
                                                            col_s, w_s, N_EDGES);

  const int MT = (N_NODES + 127) >> 7;  // 157 M-tiles

  // ---------------- layer 1: K=6, 1152 -> 1152 ----------------
  wtrans_kernel<<<6 * 36 * 36, dim3(32, 8), 0, stream>>>(W1, Wt, 6, 1152, 1152);
  cast_x_kernel<<<(N_NODES * 1152 / 4 + 255) / 256, 256, 0, stream>>>(x, TxP,
                                                                      N_NODES * 1152 / 4);
  {
    const int F = 1152, NO = 1152, nb = 9;
    size_t wsl = (size_t)NO * F;  // per-k weight slice elements
    // k=0: acc = Tx0@W0 + b
    gemm_kernel<0><<<MT * nb, 256, 0, stream>>>(TxP, Wt, b1, accb, nullptr, N_NODES, NO, F, 0);
    // k=1
    prop_kernel<1152><<<N_NODES, 256, 0, stream>>>(row_ptr, col_s, w_s, TxP, nullptr, TxQ);
    gemm_kernel<1><<<MT * nb, 256, 0, stream>>>(TxQ, Wt + wsl, b1, accb, nullptr, N_NODES, NO, F, 0);
    // k=2..4 (rolling in place), k=5 final
    prop_kernel<1152><<<N_NODES, 256, 0, stream>>>(row_ptr, col_s, w_s, TxQ, TxP, TxP);
    gemm_kernel<1><<<MT * nb, 256, 0, stream>>>(TxP, Wt + 2 * wsl, b1, accb, nullptr, N_NODES, NO, F, 0);
    prop_kernel<1152><<<N_NODES, 256, 0, stream>>>(row_ptr, col_s, w_s, TxP, TxQ, TxQ);
    gemm_kernel<1><<<MT * nb, 256, 0, stream>>>(TxQ, Wt + 3 * wsl, b1, accb, nullptr, N_NODES, NO, F, 0);
    prop_kernel<1152><<<N_NODES, 256, 0, stream>>>(row_ptr, col_s, w_s, TxQ, TxP, TxP);
    gemm_kernel<1><<<MT * nb, 256, 0, stream>>>(TxP, Wt + 4 * wsl, b1, accb, nullptr, N_NODES, NO, F, 0);
    prop_kernel<1152><<<N_NODES, 256, 0, stream>>>(row_ptr, col_s, w_s, TxP, TxQ, TxQ);
    // FINAL: h1 = relu(acc + Tx5@W5) -> TxP (dead), stride 1152
    gemm_kernel<2><<<MT * nb, 256, 0, stream>>>(TxQ, Wt + 5 * wsl, b1, accb, TxP, N_NODES, NO, F, 1152);
  }

  // ---------------- layer 2: K=5, 1152 -> 576 ----------------
  wtrans_kernel<<<5 * 36 * 18, dim3(32, 8), 0, stream>>>(W2, Wt, 5, 1152, 576);
  {
    const int F = 1152, NO = 576, nb = 5;
    size_t wsl = (size_t)NO * F;
    gemm_kernel<0><<<MT * nb, 256, 0, stream>>>(TxP, Wt, b2, accb, nullptr, N_NODES, NO, F, 0);
    prop_kernel<1152><<<N_NODES, 256, 0, stream>>>(row_ptr, col_s, w_s, TxP, nullptr, TxQ);
    gemm_kernel<1><<<MT * nb, 256, 0, stream>>>(TxQ, Wt + wsl, b2, accb, nullptr, N_NODES, NO, F, 0);
    prop_kernel<1152><<<N_NODES, 256, 0, stream>>>(row_ptr, col_s, w_s, TxQ, TxP, TxP);
    gemm_kernel<1><<<MT * nb, 256, 0, stream>>>(TxP, Wt + 2 * wsl, b2, accb, nullptr, N_NODES, NO, F, 0);
    prop_kernel<1152><<<N_NODES, 256, 0, stream>>>(row_ptr, col_s, w_s, TxP, TxQ, TxQ);
    gemm_kernel<1><<<MT * nb, 256, 0, stream>>>(TxQ, Wt + 3 * wsl, b2, accb, nullptr, N_NODES, NO, F, 0);
    prop_kernel<1152><<<N_NODES, 256, 0, stream>>>(row_ptr, col_s, w_s, TxQ, TxP, TxP);
    // FINAL: h2 = relu(acc + Tx4@W4) -> TxQ (dead), stride 576
    gemm_kernel<2><<<MT * nb, 256, 0, stream>>>(TxP, Wt + 4 * wsl, b2, accb, TxQ, N_NODES, NO, F, 576);
  }

  // ---------------- layer 3: K=5, 576 -> 288 ----------------
  wtrans_kernel<<<5 * 18 * 9, dim3(32, 8), 0, stream>>>(W3, Wt, 5, 576, 288);
  {
    const int F = 576, NO = 288, nb = 3;
    size_t wsl = (size_t)NO * F;
    gemm_kernel<0><<<MT * nb, 256, 0, stream>>>(TxQ, Wt, b3, accb, nullptr, N_NODES, NO, F, 0);
    prop_kernel<576><<<N_NODES, 256, 0, stream>>>(row_ptr, col_s, w_s, TxQ, nullptr, TxP);
    gemm_kernel<1><<<MT * nb, 256, 0, stream>>>(TxP, Wt + wsl, b3, accb, nullptr, N_NODES, NO, F, 0);
    prop_kernel<576><<<N_NODES, 256, 0, stream>>>(row_ptr, col_s, w_s, TxP, TxQ, TxQ);
    gemm_kernel<1><<<MT * nb, 256, 0, stream>>>(TxQ, Wt + 2 * wsl, b3, accb, nullptr, N_NODES, NO, F, 0);
    prop_kernel<576><<<N_NODES, 256, 0, stream>>>(row_ptr, col_s, w_s, TxQ, TxP, TxP);
    gemm_kernel<1><<<MT * nb, 256, 0, stream>>>(TxP, Wt + 3 * wsl, b3, accb, nullptr, N_NODES, NO, F, 0);
    prop_kernel<576><<<N_NODES, 256, 0, stream>>>(row_ptr, col_s, w_s, TxP, TxQ, TxQ);
    // FINAL: out = relu(acc + Tx4@W4) fp32 -> d_out
    gemm_kernel<3><<<MT * nb, 256, 0, stream>>>(TxQ, Wt + 4 * wsl, b3, accb, d_out, N_NODES, NO, F, 0);
  }
}

// Round 3
// 3100.103 us; speedup vs baseline: 1.6518x; 1.6518x over previous
//
#include <hip/hip_runtime.h>
#include <hip/hip_bf16.h>

#define N_NODES 20000
#define N_EDGES 320000

typedef __attribute__((ext_vector_type(8))) short shortx8;
typedef __attribute__((ext_vector_type(4))) float floatx4;
using bf16 = __hip_bfloat16;

__device__ inline float b2f(unsigned short u) {
  union { unsigned int i; float f; } x;
  x.i = ((unsigned int)u) << 16;
  return x.f;
}
__device__ inline unsigned short f2b(float f) {
  bf16 h(f);
  return *(unsigned short*)&h;
}

// ---------------- graph prep ----------------

__global__ void zero_kernel(int* p, int n) {
  int i = blockIdx.x * 256 + threadIdx.x;
  if (i < n) p[i] = 0;
}

__global__ void deg_kernel(const int* __restrict__ row, const int* __restrict__ col,
                           int* __restrict__ deg, int nE) {
  int e = blockIdx.x * 256 + threadIdx.x;
  if (e >= nE) return;
  int r = row[e], c = col[e];
  if (r != c) atomicAdd(&deg[r], 1);
}

__global__ void dis_kernel(const int* __restrict__ deg, float* __restrict__ dis, int n) {
  int i = blockIdx.x * 256 + threadIdx.x;
  if (i >= n) return;
  int d = deg[i];
  dis[i] = (d > 0) ? (1.0f / sqrtf((float)d)) : 0.0f;
}

// single-block exclusive scan of deg[0..n) -> row_ptr[0..n], copy to cursor
__global__ __launch_bounds__(1024) void scan_kernel(const int* __restrict__ deg,
                                                    int* __restrict__ row_ptr,
                                                    int* __restrict__ cursor, int n) {
  __shared__ int part[1024];
  int t = threadIdx.x;
  int base = t * 20;
  int loc[20];
  int s = 0;
#pragma unroll
  for (int i = 0; i < 20; i++) {
    int idx = base + i;
    int v = (idx < n) ? deg[idx] : 0;
    loc[i] = s;
    s += v;
  }
  part[t] = s;
  __syncthreads();
  for (int offd = 1; offd < 1024; offd <<= 1) {
    int v = (t >= offd) ? part[t - offd] : 0;
    __syncthreads();
    part[t] += v;
    __syncthreads();
  }
  int basev = (t > 0) ? part[t - 1] : 0;
#pragma unroll
  for (int i = 0; i < 20; i++) {
    int idx = base + i;
    if (idx < n) {
      int rp = basev + loc[i];
      row_ptr[idx] = rp;
      cursor[idx] = rp;
    }
  }
  if (t == 1023) row_ptr[n] = part[1023];
}

__global__ void scatter_kernel(const int* __restrict__ row, const int* __restrict__ col,
                               const float* __restrict__ dis, int* __restrict__ cursor,
                               int* __restrict__ col_s, float* __restrict__ w_s, int nE) {
  int e = blockIdx.x * 256 + threadIdx.x;
  if (e >= nE) return;
  int r = row[e], c = col[e];
  if (r == c) return;
  int p = atomicAdd(&cursor[r], 1);
  col_s[p] = c;
  w_s[p] = -dis[r] * dis[c];
}

// ---------------- weight prep: W (K,I,J) fp32 -> Wt[k][j][i] bf16 ----------------

__global__ void wtrans_kernel(const float* __restrict__ W, bf16* __restrict__ Wt,
                              int K_, int I, int J) {
  __shared__ float tile[32][33];
  int jt = blockIdx.x % (J / 32);
  int rest = blockIdx.x / (J / 32);
  int it = rest % (I / 32);
  int k = rest / (I / 32);
  int tx = threadIdx.x, ty = threadIdx.y;
  const float* src = W + (size_t)k * I * J;
  for (int r = ty; r < 32; r += 8)
    tile[r][tx] = src[(size_t)(it * 32 + r) * J + jt * 32 + tx];
  __syncthreads();
  for (int r = ty; r < 32; r += 8) {
    int j = jt * 32 + r;
    Wt[((size_t)k * J + j) * I + it * 32 + tx] = bf16(tile[tx][r]);
  }
}

// ---------------- cast x (fp32, N x 1152 flat) -> bf16 ----------------

__global__ void cast_x_kernel(const float* __restrict__ x, bf16* __restrict__ dst, int n4) {
  int idx = blockIdx.x * 256 + threadIdx.x;
  if (idx >= n4) return;
  int flat = idx * 4;
  float4 v = *(const float4*)(x + flat);
  dst[flat + 0] = bf16(v.x);
  dst[flat + 1] = bf16(v.y);
  dst[flat + 2] = bf16(v.z);
  dst[flat + 3] = bf16(v.w);
}

// ---------------- prop: dst = L~ src, or dst = 2*L~ src - tx0 (tx0 may alias dst) ----
// one block per node; ushort4 (8B) gathers; edge loop unrolled x4 for MLP.
// No __restrict__ on tx0/dst: for k>=2 they alias (in-place; each block owns its row).

template <int F, int BLK>
__global__ __launch_bounds__(BLK) void prop_kernel(
    const int* __restrict__ row_ptr, const int* __restrict__ col_s,
    const float* __restrict__ w_s, const bf16* __restrict__ src,
    const bf16* tx0, bf16* dst) {
  constexpr int C = F / 4;                 // ushort4 chunks per row
  constexpr int NJ = (C + BLK - 1) / BLK;  // chunk sweeps per thread
  int node = blockIdx.x;
  int t = threadIdx.x;
  int e0 = row_ptr[node], e1 = row_ptr[node + 1];
  float acc[NJ][4];
#pragma unroll
  for (int j = 0; j < NJ; j++)
#pragma unroll
    for (int q = 0; q < 4; q++) acc[j][q] = 0.0f;

  const unsigned short* sp = (const unsigned short*)src;
  int e = e0;
  for (; e + 4 <= e1; e += 4) {
    int c0 = col_s[e + 0], c1 = col_s[e + 1], c2 = col_s[e + 2], c3 = col_s[e + 3];
    float w0 = w_s[e + 0], w1 = w_s[e + 1], w2 = w_s[e + 2], w3 = w_s[e + 3];
    ushort4 v0[NJ], v1[NJ], v2[NJ], v3[NJ];
#pragma unroll
    for (int j = 0; j < NJ; j++) {
      int ci = t + j * BLK;
      if (ci < C) {
        v0[j] = *(const ushort4*)(sp + (size_t)c0 * F + ci * 4);
        v1[j] = *(const ushort4*)(sp + (size_t)c1 * F + ci * 4);
        v2[j] = *(const ushort4*)(sp + (size_t)c2 * F + ci * 4);
        v3[j] = *(const ushort4*)(sp + (size_t)c3 * F + ci * 4);
      }
    }
#pragma unroll
    for (int j = 0; j < NJ; j++) {
      int ci = t + j * BLK;
      if (ci < C) {
        acc[j][0] += w0 * b2f(v0[j].x) + w1 * b2f(v1[j].x) + w2 * b2f(v2[j].x) + w3 * b2f(v3[j].x);
        acc[j][1] += w0 * b2f(v0[j].y) + w1 * b2f(v1[j].y) + w2 * b2f(v2[j].y) + w3 * b2f(v3[j].y);
        acc[j][2] += w0 * b2f(v0[j].z) + w1 * b2f(v1[j].z) + w2 * b2f(v2[j].z) + w3 * b2f(v3[j].z);
        acc[j][3] += w0 * b2f(v0[j].w) + w1 * b2f(v1[j].w) + w2 * b2f(v2[j].w) + w3 * b2f(v3[j].w);
      }
    }
  }
  for (; e < e1; e++) {
    int c = col_s[e];
    float w = w_s[e];
#pragma unroll
    for (int j = 0; j < NJ; j++) {
      int ci = t + j * BLK;
      if (ci < C) {
        ushort4 v = *(const ushort4*)(sp + (size_t)c * F + ci * 4);
        acc[j][0] += w * b2f(v.x);
        acc[j][1] += w * b2f(v.y);
        acc[j][2] += w * b2f(v.z);
        acc[j][3] += w * b2f(v.w);
      }
    }
  }

  unsigned short* dp = (unsigned short*)dst + (size_t)node * F;
  if (tx0) {
    const unsigned short* t0 = (const unsigned short*)tx0 + (size_t)node * F;
#pragma unroll
    for (int j = 0; j < NJ; j++) {
      int ci = t + j * BLK;
      if (ci < C) {
        ushort4 tv = *(const ushort4*)(t0 + ci * 4);
        ushort4 o;
        o.x = f2b(2.0f * acc[j][0] - b2f(tv.x));
        o.y = f2b(2.0f * acc[j][1] - b2f(tv.y));
        o.z = f2b(2.0f * acc[j][2] - b2f(tv.z));
        o.w = f2b(2.0f * acc[j][3] - b2f(tv.w));
        *(ushort4*)(dp + ci * 4) = o;
      }
    }
  } else {
#pragma unroll
    for (int j = 0; j < NJ; j++) {
      int ci = t + j * BLK;
      if (ci < C) {
        ushort4 o;
        o.x = f2b(acc[j][0]);
        o.y = f2b(acc[j][1]);
        o.z = f2b(acc[j][2]);
        o.w = f2b(acc[j][3]);
        *(ushort4*)(dp + ci * 4) = o;
      }
    }
  }
}

// ---------------- bf16 MFMA GEMM with accumulation modes ----------------
// A: M x Kt bf16 row-major; Bt: Nout x Kt bf16 (B transposed).
// MODE 0 (INIT):  accbuf = A@B + bias          (fp32, stride Nout)
// MODE 1 (ACCUM): accbuf += A@B
// MODE 2 (FINAL_BF16): dst = relu(accbuf + A@B) cast bf16, stride dstLd
// MODE 3 (FINAL_F32):  dst = relu(accbuf + A@B) fp32, stride Nout

template <int MODE>
__global__ __launch_bounds__(256) void gemm_kernel(
    const bf16* __restrict__ A, const bf16* __restrict__ Bt,
    const float* __restrict__ bias, float* __restrict__ accbuf,
    void* __restrict__ dst, int M, int Nout, int Kt, int dstLd) {
  __shared__ bf16 As[128][40];
  __shared__ bf16 Bs[128][40];
  int nb = (Nout + 127) >> 7;
  int bm = blockIdx.x / nb;
  int bn = blockIdx.x - bm * nb;
  int m0 = bm << 7, n0 = bn << 7;
  int t = threadIdx.x;
  int lane = t & 63;
  int wave = t >> 6;
  int wm = wave & 1, wn = wave >> 1;
  int l16 = lane & 15;
  int k8 = (lane >> 4) << 3;
  floatx4 acc[4][4] = {};
  int rr0 = t >> 2;
  int cc = (t & 3) << 3;  // element offset within 32-wide K slab
  for (int kt = 0; kt < Kt; kt += 32) {
#pragma unroll
    for (int p = 0; p < 2; p++) {
      int rr = rr0 + p * 64;
      uint4 av = make_uint4(0, 0, 0, 0);
      int ga = m0 + rr;
      if (ga < M) av = *(const uint4*)(A + (size_t)ga * Kt + kt + cc);
      *(uint4*)(&As[rr][cc]) = av;
      uint4 bv = make_uint4(0, 0, 0, 0);
      int gb = n0 + rr;
      if (gb < Nout) bv = *(const uint4*)(Bt + (size_t)gb * Kt + kt + cc);
      *(uint4*)(&Bs[rr][cc]) = bv;
    }
    __syncthreads();
    shortx8 af[4], bfr[4];
#pragma unroll
    for (int i = 0; i < 4; i++)
      af[i] = *(const shortx8*)(&As[(wm << 6) + (i << 4) + l16][k8]);
#pragma unroll
    for (int j = 0; j < 4; j++)
      bfr[j] = *(const shortx8*)(&Bs[(wn << 6) + (j << 4) + l16][k8]);
#pragma unroll
    for (int i = 0; i < 4; i++)
#pragma unroll
      for (int j = 0; j < 4; j++)
        acc[i][j] = __builtin_amdgcn_mfma_f32_16x16x32_bf16(af[i], bfr[j], acc[i][j], 0, 0, 0);
    __syncthreads();
  }
  // epilogue: C/D layout col = lane&15, row = (lane>>4)*4 + reg
  int lq = lane >> 4;
#pragma unroll
  for (int j = 0; j < 4; j++) {
    int colg = n0 + (wn << 6) + (j << 4) + l16;
    if (colg >= Nout) continue;
    float bv = (MODE == 0) ? bias[colg] : 0.0f;
#pragma unroll
    for (int i = 0; i < 4; i++) {
      int rowb = m0 + (wm << 6) + (i << 4) + (lq << 2);
#pragma unroll
      for (int q = 0; q < 4; q++) {
        int rowg = rowb + q;
        if (rowg >= M) continue;
        float v = acc[i][j][q];
        size_t aidx = (size_t)rowg * Nout + colg;
        if constexpr (MODE == 0) {
          accbuf[aidx] = v + bv;
        } else if constexpr (MODE == 1) {
          accbuf[aidx] += v;
        } else if constexpr (MODE == 2) {
          float s = fmaxf(accbuf[aidx] + v, 0.0f);
          ((bf16*)dst)[(size_t)rowg * dstLd + colg] = bf16(s);
        } else {
          float s = fmaxf(accbuf[aidx] + v, 0.0f);
          ((float*)dst)[(size_t)rowg * Nout + colg] = s;
        }
      }
    }
  }
}

// ---------------- host launch ----------------

extern "C" void kernel_launch(void* const* d_in, const int* in_sizes, int n_in,
                              void* d_out, int out_size, void* d_ws, size_t ws_size,
                              hipStream_t stream) {
  const float* x = (const float*)d_in[0];
  const int* row = (const int*)d_in[1];
  const int* col = (const int*)d_in[2];
  const float* W1 = (const float*)d_in[3];
  const float* b1 = (const float*)d_in[4];
  const float* W2 = (const float*)d_in[5];
  const float* b2 = (const float*)d_in[6];
  const float* W3 = (const float*)d_in[7];
  const float* b3 = (const float*)d_in[8];

  char* ws = (char*)d_ws;
  size_t off = 0;
  auto alloc = [&](size_t bytes) -> void* {
    void* p = ws + off;
    off += (bytes + 255) & ~(size_t)255;
    return p;
  };

  // ~194 MiB total
  bf16* Wt = (bf16*)alloc((size_t)6 * 1152 * 1152 * 2);  // reused per layer
  int* deg = (int*)alloc(N_NODES * 4);
  float* dis = (float*)alloc(N_NODES * 4);
  int* row_ptr = (int*)alloc((N_NODES + 1) * 4);
  int* cursor = (int*)alloc(N_NODES * 4);
  int* col_s = (int*)alloc(N_EDGES * 4);
  float* w_s = (float*)alloc(N_EDGES * 4);
  bf16* TxP = (bf16*)alloc((size_t)N_NODES * 1152 * 2);
  bf16* TxQ = (bf16*)alloc((size_t)N_NODES * 1152 * 2);
  float* accb = (float*)alloc((size_t)N_NODES * 1152 * 4);
  if (off > ws_size) return;  // workspace too small -> validation will fail loudly

  // graph prep
  zero_kernel<<<(N_NODES + 255) / 256, 256, 0, stream>>>(deg, N_NODES);
  deg_kernel<<<(N_EDGES + 255) / 256, 256, 0, stream>>>(row, col, deg, N_EDGES);
  dis_kernel<<<(N_NODES + 255) / 256, 256, 0, stream>>>(deg, dis, N_NODES);
  scan_kernel<<<1, 1024, 0, stream>>>(deg, row_ptr, cursor, N_NODES);
  scatter_kernel<<<(N_EDGES + 255) / 256, 256, 0, stream>>>(row, col, dis, cursor,
                                                            col_s, w_s, N_EDGES);

  const int MT = (N_NODES + 127) >> 7;  // 157 M-tiles

  // ---------------- layer 1: K=6, 1152 -> 1152 ----------------
  wtrans_kernel<<<6 * 36 * 36, dim3(32, 8), 0, stream>>>(W1, Wt, 6, 1152, 1152);
  cast_x_kernel<<<(N_NODES * 1152 / 4 + 255) / 256, 256, 0, stream>>>(x, TxP,
                                                                      N_NODES * 1152 / 4);
  {
    const int F = 1152, NO = 1152, nb = 9;
    size_t wsl = (size_t)NO * F;  // per-k weight slice elements
    gemm_kernel<0><<<MT * nb, 256, 0, stream>>>(TxP, Wt, b1, accb, nullptr, N_NODES, NO, F, 0);
    prop_kernel<1152, 256><<<N_NODES, 256, 0, stream>>>(row_ptr, col_s, w_s, TxP, nullptr, TxQ);
    gemm_kernel<1><<<MT * nb, 256, 0, stream>>>(TxQ, Wt + wsl, b1, accb, nullptr, N_NODES, NO, F, 0);
    prop_kernel<1152, 256><<<N_NODES, 256, 0, stream>>>(row_ptr, col_s, w_s, TxQ, TxP, TxP);
    gemm_kernel<1><<<MT * nb, 256, 0, stream>>>(TxP, Wt + 2 * wsl, b1, accb, nullptr, N_NODES, NO, F, 0);
    prop_kernel<1152, 256><<<N_NODES, 256, 0, stream>>>(row_ptr, col_s, w_s, TxP, TxQ, TxQ);
    gemm_kernel<1><<<MT * nb, 256, 0, stream>>>(TxQ, Wt + 3 * wsl, b1, accb, nullptr, N_NODES, NO, F, 0);
    prop_kernel<1152, 256><<<N_NODES, 256, 0, stream>>>(row_ptr, col_s, w_s, TxQ, TxP, TxP);
    gemm_kernel<1><<<MT * nb, 256, 0, stream>>>(TxP, Wt + 4 * wsl, b1, accb, nullptr, N_NODES, NO, F, 0);
    prop_kernel<1152, 256><<<N_NODES, 256, 0, stream>>>(row_ptr, col_s, w_s, TxP, TxQ, TxQ);
    // FINAL: h1 = relu(acc + Tx5@W5) -> TxP (dead), stride 1152
    gemm_kernel<2><<<MT * nb, 256, 0, stream>>>(TxQ, Wt + 5 * wsl, b1, accb, TxP, N_NODES, NO, F, 1152);
  }

  // ---------------- layer 2: K=5, 1152 -> 576 ----------------
  wtrans_kernel<<<5 * 36 * 18, dim3(32, 8), 0, stream>>>(W2, Wt, 5, 1152, 576);
  {
    const int F = 1152, NO = 576, nb = 5;
    size_t wsl = (size_t)NO * F;
    gemm_kernel<0><<<MT * nb, 256, 0, stream>>>(TxP, Wt, b2, accb, nullptr, N_NODES, NO, F, 0);
    prop_kernel<1152, 256><<<N_NODES, 256, 0, stream>>>(row_ptr, col_s, w_s, TxP, nullptr, TxQ);
    gemm_kernel<1><<<MT * nb, 256, 0, stream>>>(TxQ, Wt + wsl, b2, accb, nullptr, N_NODES, NO, F, 0);
    prop_kernel<1152, 256><<<N_NODES, 256, 0, stream>>>(row_ptr, col_s, w_s, TxQ, TxP, TxP);
    gemm_kernel<1><<<MT * nb, 256, 0, stream>>>(TxP, Wt + 2 * wsl, b2, accb, nullptr, N_NODES, NO, F, 0);
    prop_kernel<1152, 256><<<N_NODES, 256, 0, stream>>>(row_ptr, col_s, w_s, TxP, TxQ, TxQ);
    gemm_kernel<1><<<MT * nb, 256, 0, stream>>>(TxQ, Wt + 3 * wsl, b2, accb, nullptr, N_NODES, NO, F, 0);
    prop_kernel<1152, 256><<<N_NODES, 256, 0, stream>>>(row_ptr, col_s, w_s, TxQ, TxP, TxP);
    // FINAL: h2 = relu(acc + Tx4@W4) -> TxQ (dead), stride 576
    gemm_kernel<2><<<MT * nb, 256, 0, stream>>>(TxP, Wt + 4 * wsl, b2, accb, TxQ, N_NODES, NO, F, 576);
  }

  // ---------------- layer 3: K=5, 576 -> 288 ----------------
  wtrans_kernel<<<5 * 18 * 9, dim3(32, 8), 0, stream>>>(W3, Wt, 5, 576, 288);
  {
    const int F = 576, NO = 288, nb = 3;
    size_t wsl = (size_t)NO * F;
    gemm_kernel<0><<<MT * nb, 256, 0, stream>>>(TxQ, Wt, b3, accb, nullptr, N_NODES, NO, F, 0);
    prop_kernel<576, 128><<<N_NODES, 128, 0, stream>>>(row_ptr, col_s, w_s, TxQ, nullptr, TxP);
    gemm_kernel<1><<<MT * nb, 256, 0, stream>>>(TxP, Wt + wsl, b3, accb, nullptr, N_NODES, NO, F, 0);
    prop_kernel<576, 128><<<N_NODES, 128, 0, stream>>>(row_ptr, col_s, w_s, TxP, TxQ, TxQ);
    gemm_kernel<1><<<MT * nb, 256, 0, stream>>>(TxQ, Wt + 2 * wsl, b3, accb, nullptr, N_NODES, NO, F, 0);
    prop_kernel<576, 128><<<N_NODES, 128, 0, stream>>>(row_ptr, col_s, w_s, TxQ, TxP, TxP);
    gemm_kernel<1><<<MT * nb, 256, 0, stream>>>(TxP, Wt + 3 * wsl, b3, accb, nullptr, N_NODES, NO, F, 0);
    prop_kernel<576, 128><<<N_NODES, 128, 0, stream>>>(row_ptr, col_s, w_s, TxP, TxQ, TxQ);
    // FINAL: out = relu(acc + Tx4@W4) fp32 -> d_out
    gemm_kernel<3><<<MT * nb, 256, 0, stream>>>(TxQ, Wt + 4 * wsl, b3, accb, d_out, N_NODES, NO, F, 0);
  }
}

// Round 4
// 2513.639 us; speedup vs baseline: 2.0372x; 1.2333x over previous
//
#include <hip/hip_runtime.h>
#include <hip/hip_bf16.h>

#define N_NODES 20000
#define N_EDGES 320000

typedef __attribute__((ext_vector_type(8))) short shortx8;
typedef __attribute__((ext_vector_type(4))) float floatx4;
using bf16 = __hip_bfloat16;

typedef __attribute__((address_space(1))) const unsigned int GuT;
typedef __attribute__((address_space(3))) unsigned int LuT;
__device__ __forceinline__ void gl2lds16(const bf16* g, bf16* l) {
  // async global->LDS, 16B/lane; LDS dest = wave-uniform base + lane*16
  __builtin_amdgcn_global_load_lds((GuT*)g, (LuT*)l, 16, 0, 0);
}

__device__ inline float b2f(unsigned short u) {
  union { unsigned int i; float f; } x;
  x.i = ((unsigned int)u) << 16;
  return x.f;
}
__device__ inline unsigned short f2b(float f) {
  bf16 h(f);
  return *(unsigned short*)&h;
}

// ---------------- graph prep ----------------

__global__ void zero_kernel(int* p, int n) {
  int i = blockIdx.x * 256 + threadIdx.x;
  if (i < n) p[i] = 0;
}

__global__ void deg_kernel(const int* __restrict__ row, const int* __restrict__ col,
                           int* __restrict__ deg, int nE) {
  int e = blockIdx.x * 256 + threadIdx.x;
  if (e >= nE) return;
  int r = row[e], c = col[e];
  if (r != c) atomicAdd(&deg[r], 1);
}

__global__ void dis_kernel(const int* __restrict__ deg, float* __restrict__ dis, int n) {
  int i = blockIdx.x * 256 + threadIdx.x;
  if (i >= n) return;
  int d = deg[i];
  dis[i] = (d > 0) ? (1.0f / sqrtf((float)d)) : 0.0f;
}

// single-block exclusive scan of deg[0..n) -> row_ptr[0..n], copy to cursor
__global__ __launch_bounds__(1024) void scan_kernel(const int* __restrict__ deg,
                                                    int* __restrict__ row_ptr,
                                                    int* __restrict__ cursor, int n) {
  __shared__ int part[1024];
  int t = threadIdx.x;
  int base = t * 20;
  int loc[20];
  int s = 0;
#pragma unroll
  for (int i = 0; i < 20; i++) {
    int idx = base + i;
    int v = (idx < n) ? deg[idx] : 0;
    loc[i] = s;
    s += v;
  }
  part[t] = s;
  __syncthreads();
  for (int offd = 1; offd < 1024; offd <<= 1) {
    int v = (t >= offd) ? part[t - offd] : 0;
    __syncthreads();
    part[t] += v;
    __syncthreads();
  }
  int basev = (t > 0) ? part[t - 1] : 0;
#pragma unroll
  for (int i = 0; i < 20; i++) {
    int idx = base + i;
    if (idx < n) {
      int rp = basev + loc[i];
      row_ptr[idx] = rp;
      cursor[idx] = rp;
    }
  }
  if (t == 1023) row_ptr[n] = part[1023];
}

__global__ void scatter_kernel(const int* __restrict__ row, const int* __restrict__ col,
                               const float* __restrict__ dis, int* __restrict__ cursor,
                               int* __restrict__ col_s, float* __restrict__ w_s, int nE) {
  int e = blockIdx.x * 256 + threadIdx.x;
  if (e >= nE) return;
  int r = row[e], c = col[e];
  if (r == c) return;
  int p = atomicAdd(&cursor[r], 1);
  col_s[p] = c;
  w_s[p] = -dis[r] * dis[c];
}

// ---------------- weight prep: W (K,I,J) fp32 -> Wt[k][j][i] bf16 ----------------

__global__ void wtrans_kernel(const float* __restrict__ W, bf16* __restrict__ Wt,
                              int K_, int I, int J) {
  __shared__ float tile[32][33];
  int jt = blockIdx.x % (J / 32);
  int rest = blockIdx.x / (J / 32);
  int it = rest % (I / 32);
  int k = rest / (I / 32);
  int tx = threadIdx.x, ty = threadIdx.y;
  const float* src = W + (size_t)k * I * J;
  for (int r = ty; r < 32; r += 8)
    tile[r][tx] = src[(size_t)(it * 32 + r) * J + jt * 32 + tx];
  __syncthreads();
  for (int r = ty; r < 32; r += 8) {
    int j = jt * 32 + r;
    Wt[((size_t)k * J + j) * I + it * 32 + tx] = bf16(tile[tx][r]);
  }
}

// ---------------- cast x (fp32, N x 1152 flat) -> bf16 ----------------

__global__ void cast_x_kernel(const float* __restrict__ x, bf16* __restrict__ dst, int n4) {
  int idx = blockIdx.x * 256 + threadIdx.x;
  if (idx >= n4) return;
  int flat = idx * 4;
  float4 v = *(const float4*)(x + flat);
  dst[flat + 0] = bf16(v.x);
  dst[flat + 1] = bf16(v.y);
  dst[flat + 2] = bf16(v.z);
  dst[flat + 3] = bf16(v.w);
}

// ---------------- prop: dst = L~ src, or dst = 2*L~ src - tx0 (tx0 may alias dst) ----
// 320 threads/block, one block per node; exactly one VEC-chunk per thread (C=288).
// Edge loop unrolled x8 for memory-level parallelism.

template <int F, int VEC>
__global__ __launch_bounds__(320) void prop_kernel(
    const int* __restrict__ row_ptr, const int* __restrict__ col_s,
    const float* __restrict__ w_s, const bf16* __restrict__ src,
    const bf16* tx0, bf16* dst) {
  constexpr int C = F / VEC;  // 288
  int node = blockIdx.x;
  int t = threadIdx.x;
  bool act = t < C;
  int fb = t * VEC;  // feature base for this thread
  int e0 = row_ptr[node], e1 = row_ptr[node + 1];
  float acc[VEC];
#pragma unroll
  for (int q = 0; q < VEC; q++) acc[q] = 0.0f;

  const unsigned short* sp = (const unsigned short*)src;
  int e = e0;
  for (; e + 8 <= e1; e += 8) {
    int cs[8];
    float wv[8];
#pragma unroll
    for (int u = 0; u < 8; u++) {
      cs[u] = col_s[e + u];
      wv[u] = w_s[e + u];
    }
    if (act) {
      if constexpr (VEC == 4) {
        ushort4 v[8];
#pragma unroll
        for (int u = 0; u < 8; u++) v[u] = *(const ushort4*)(sp + (size_t)cs[u] * F + fb);
#pragma unroll
        for (int u = 0; u < 8; u++) {
          acc[0] += wv[u] * b2f(v[u].x);
          acc[1] += wv[u] * b2f(v[u].y);
          acc[2] += wv[u] * b2f(v[u].z);
          acc[3] += wv[u] * b2f(v[u].w);
        }
      } else {
        ushort2 v[8];
#pragma unroll
        for (int u = 0; u < 8; u++) v[u] = *(const ushort2*)(sp + (size_t)cs[u] * F + fb);
#pragma unroll
        for (int u = 0; u < 8; u++) {
          acc[0] += wv[u] * b2f(v[u].x);
          acc[1] += wv[u] * b2f(v[u].y);
        }
      }
    }
  }
  for (; e < e1; e++) {
    int c = col_s[e];
    float w = w_s[e];
    if (act) {
      if constexpr (VEC == 4) {
        ushort4 v = *(const ushort4*)(sp + (size_t)c * F + fb);
        acc[0] += w * b2f(v.x);
        acc[1] += w * b2f(v.y);
        acc[2] += w * b2f(v.z);
        acc[3] += w * b2f(v.w);
      } else {
        ushort2 v = *(const ushort2*)(sp + (size_t)c * F + fb);
        acc[0] += w * b2f(v.x);
        acc[1] += w * b2f(v.y);
      }
    }
  }

  if (!act) return;
  unsigned short* dp = (unsigned short*)dst + (size_t)node * F + fb;
  if (tx0) {
    const unsigned short* t0 = (const unsigned short*)tx0 + (size_t)node * F + fb;
    if constexpr (VEC == 4) {
      ushort4 tv = *(const ushort4*)t0;
      ushort4 o;
      o.x = f2b(2.0f * acc[0] - b2f(tv.x));
      o.y = f2b(2.0f * acc[1] - b2f(tv.y));
      o.z = f2b(2.0f * acc[2] - b2f(tv.z));
      o.w = f2b(2.0f * acc[3] - b2f(tv.w));
      *(ushort4*)dp = o;
    } else {
      ushort2 tv = *(const ushort2*)t0;
      ushort2 o;
      o.x = f2b(2.0f * acc[0] - b2f(tv.x));
      o.y = f2b(2.0f * acc[1] - b2f(tv.y));
      *(ushort2*)dp = o;
    }
  } else {
    if constexpr (VEC == 4) {
      ushort4 o;
      o.x = f2b(acc[0]);
      o.y = f2b(acc[1]);
      o.z = f2b(acc[2]);
      o.w = f2b(acc[3]);
      *(ushort4*)dp = o;
    } else {
      ushort2 o;
      o.x = f2b(acc[0]);
      o.y = f2b(acc[1]);
      *(ushort2*)dp = o;
    }
  }
}

// ---------------- bf16 MFMA GEMM (m97 structure) with K segments + acc modes -------
// Computes sum over segments of A_s @ B_s^T. BK=32, unpadded 128x32 LDS tiles,
// global_load_lds 16B staging, ds_read_b128 fragments, 16 MFMA/wave/iter.
// MODE 0 (INIT):  accbuf = result + bias     (fp32, stride Nout)
// MODE 1 (ACCUM): accbuf += result
// MODE 2 (FINAL_BF16): dst = relu(accbuf + result) bf16, stride dstLd
// MODE 3 (FINAL_F32):  dst = relu(accbuf + result) fp32, stride Nout

template <int MODE, int NSEG>
__global__ __launch_bounds__(256) void gemm_kernel(
    const bf16* __restrict__ A1, const bf16* __restrict__ B1,
    const bf16* __restrict__ A2, const bf16* __restrict__ B2,
    const float* __restrict__ bias, float* __restrict__ accbuf,
    void* __restrict__ dst, int M, int Nout, int Kt, int dstLd) {
  __shared__ bf16 As[128 * 32];
  __shared__ bf16 Bs[128 * 32];
  int nb = (Nout + 127) >> 7;
  int bm = blockIdx.x / nb;
  int bn = blockIdx.x - bm * nb;
  int m0 = bm << 7, n0 = bn << 7;
  int t = threadIdx.x;
  int lane = t & 63;
  int wave = t >> 6;
  int wm = wave & 1, wn = wave >> 1;
  int l16 = lane & 15;
  int k8 = (lane >> 4) << 3;
  floatx4 acc[4][4] = {};

  // staging geometry: inst covers 16 rows, 4 lanes/row, 8 bf16 (16B) per lane
  int srow = lane >> 2;         // 0..15 within inst
  int scol = (lane & 3) << 3;   // 0,8,16,24

#pragma unroll 1
  for (int seg = 0; seg < NSEG; seg++) {
    const bf16* A = (seg == 0) ? A1 : A2;
    const bf16* Bt = (seg == 0) ? B1 : B2;
#pragma unroll 1
    for (int kt = 0; kt < Kt; kt += 32) {
#pragma unroll
      for (int q = 0; q < 2; q++) {
        int inst = (wave << 1) + q;
        int r = (inst << 4) + srow;
        int ga = m0 + r;
        if (ga < M)
          gl2lds16(A + (size_t)ga * Kt + kt + scol, &As[inst << 9]);
        int gb = n0 + r;
        if (gb < Nout)
          gl2lds16(Bt + (size_t)gb * Kt + kt + scol, &Bs[inst << 9]);
      }
      __syncthreads();
      shortx8 af[4], bfr[4];
#pragma unroll
      for (int i = 0; i < 4; i++)
        af[i] = *(const shortx8*)&As[(((wm << 6) + (i << 4) + l16) << 5) + k8];
#pragma unroll
      for (int j = 0; j < 4; j++)
        bfr[j] = *(const shortx8*)&Bs[(((wn << 6) + (j << 4) + l16) << 5) + k8];
#pragma unroll
      for (int i = 0; i < 4; i++)
#pragma unroll
        for (int j = 0; j < 4; j++)
          acc[i][j] = __builtin_amdgcn_mfma_f32_16x16x32_bf16(af[i], bfr[j], acc[i][j], 0, 0, 0);
      __syncthreads();
    }
  }

  // epilogue: C/D layout col = lane&15, row = (lane>>4)*4 + reg
  int lq = lane >> 4;
#pragma unroll
  for (int j = 0; j < 4; j++) {
    int colg = n0 + (wn << 6) + (j << 4) + l16;
    if (colg >= Nout) continue;
    float bv = (MODE == 0) ? bias[colg] : 0.0f;
#pragma unroll
    for (int i = 0; i < 4; i++) {
      int rowb = m0 + (wm << 6) + (i << 4) + (lq << 2);
#pragma unroll
      for (int q = 0; q < 4; q++) {
        int rowg = rowb + q;
        if (rowg >= M) continue;
        float v = acc[i][j][q];
        size_t aidx = (size_t)rowg * Nout + colg;
        if constexpr (MODE == 0) {
          accbuf[aidx] = v + bv;
        } else if constexpr (MODE == 1) {
          accbuf[aidx] += v;
        } else if constexpr (MODE == 2) {
          float s = fmaxf(accbuf[aidx] + v, 0.0f);
          ((bf16*)dst)[(size_t)rowg * dstLd + colg] = bf16(s);
        } else {
          float s = fmaxf(accbuf[aidx] + v, 0.0f);
          ((float*)dst)[(size_t)rowg * Nout + colg] = s;
        }
      }
    }
  }
}

// ---------------- host launch ----------------

extern "C" void kernel_launch(void* const* d_in, const int* in_sizes, int n_in,
                              void* d_out, int out_size, void* d_ws, size_t ws_size,
                              hipStream_t stream) {
  const float* x = (const float*)d_in[0];
  const int* row = (const int*)d_in[1];
  const int* col = (const int*)d_in[2];
  const float* W1 = (const float*)d_in[3];
  const float* b1 = (const float*)d_in[4];
  const float* W2 = (const float*)d_in[5];
  const float* b2 = (const float*)d_in[6];
  const float* W3 = (const float*)d_in[7];
  const float* b3 = (const float*)d_in[8];

  char* ws = (char*)d_ws;
  size_t off = 0;
  auto alloc = [&](size_t bytes) -> void* {
    void* p = ws + off;
    off += (bytes + 255) & ~(size_t)255;
    return p;
  };

  // ~194 MiB total (known to fit from round 2/3)
  bf16* Wt = (bf16*)alloc((size_t)6 * 1152 * 1152 * 2);  // reused per layer
  int* deg = (int*)alloc(N_NODES * 4);
  float* dis = (float*)alloc(N_NODES * 4);
  int* row_ptr = (int*)alloc((N_NODES + 1) * 4);
  int* cursor = (int*)alloc(N_NODES * 4);
  int* col_s = (int*)alloc(N_EDGES * 4);
  float* w_s = (float*)alloc(N_EDGES * 4);
  bf16* TxP = (bf16*)alloc((size_t)N_NODES * 1152 * 2);
  bf16* TxQ = (bf16*)alloc((size_t)N_NODES * 1152 * 2);
  float* accb = (float*)alloc((size_t)N_NODES * 1152 * 4);
  if (off > ws_size) return;  // workspace too small -> validation fails loudly

  // graph prep
  zero_kernel<<<(N_NODES + 255) / 256, 256, 0, stream>>>(deg, N_NODES);
  deg_kernel<<<(N_EDGES + 255) / 256, 256, 0, stream>>>(row, col, deg, N_EDGES);
  dis_kernel<<<(N_NODES + 255) / 256, 256, 0, stream>>>(deg, dis, N_NODES);
  scan_kernel<<<1, 1024, 0, stream>>>(deg, row_ptr, cursor, N_NODES);
  scatter_kernel<<<(N_EDGES + 255) / 256, 256, 0, stream>>>(row, col, dis, cursor,
                                                            col_s, w_s, N_EDGES);

  const int MT = (N_NODES + 127) >> 7;  // 157 M-tiles
  const bf16* NB = nullptr;

  // ---------------- layer 1: K=6, 1152 -> 1152 ----------------
  wtrans_kernel<<<6 * 36 * 36, dim3(32, 8), 0, stream>>>(W1, Wt, 6, 1152, 1152);
  cast_x_kernel<<<(N_NODES * 1152 / 4 + 255) / 256, 256, 0, stream>>>(x, TxP,
                                                                      N_NODES * 1152 / 4);
  {
    const int F = 1152, NO = 1152, nb = 9;
    size_t wsl = (size_t)NO * F;
    // TxP=Tx0; Tx1 -> TxQ
    prop_kernel<1152, 4><<<N_NODES, 320, 0, stream>>>(row_ptr, col_s, w_s, TxP, NB, TxQ);
    // INIT pair (Tx0*W0 + Tx1*W1 + b)
    gemm_kernel<0, 2><<<MT * nb, 256, 0, stream>>>(TxP, Wt, TxQ, Wt + wsl, b1, accb,
                                                   nullptr, N_NODES, NO, F, 0);
    // Tx2 -> TxP, Tx3 -> TxQ
    prop_kernel<1152, 4><<<N_NODES, 320, 0, stream>>>(row_ptr, col_s, w_s, TxQ, TxP, TxP);
    prop_kernel<1152, 4><<<N_NODES, 320, 0, stream>>>(row_ptr, col_s, w_s, TxP, TxQ, TxQ);
    // ACCUM pair (Tx2*W2 + Tx3*W3)
    gemm_kernel<1, 2><<<MT * nb, 256, 0, stream>>>(TxP, Wt + 2 * wsl, TxQ, Wt + 3 * wsl,
                                                   b1, accb, nullptr, N_NODES, NO, F, 0);
    // Tx4 -> TxP, Tx5 -> TxQ
    prop_kernel<1152, 4><<<N_NODES, 320, 0, stream>>>(row_ptr, col_s, w_s, TxQ, TxP, TxP);
    prop_kernel<1152, 4><<<N_NODES, 320, 0, stream>>>(row_ptr, col_s, w_s, TxP, TxQ, TxQ);
    // ACCUM single (Tx4*W4)
    gemm_kernel<1, 1><<<MT * nb, 256, 0, stream>>>(TxP, Wt + 4 * wsl, NB, NB, b1, accb,
                                                   nullptr, N_NODES, NO, F, 0);
    // FINAL single (Tx5*W5) -> h1 = TxP (dead), bf16 ld 1152
    gemm_kernel<2, 1><<<MT * nb, 256, 0, stream>>>(TxQ, Wt + 5 * wsl, NB, NB, b1, accb,
                                                   TxP, N_NODES, NO, F, 1152);
  }

  // ---------------- layer 2: K=5, 1152 -> 576 ----------------
  wtrans_kernel<<<5 * 36 * 18, dim3(32, 8), 0, stream>>>(W2, Wt, 5, 1152, 576);
  {
    const int F = 1152, NO = 576, nb = 5;
    size_t wsl = (size_t)NO * F;
    // TxP=h1=Tx0; Tx1 -> TxQ
    prop_kernel<1152, 4><<<N_NODES, 320, 0, stream>>>(row_ptr, col_s, w_s, TxP, NB, TxQ);
    gemm_kernel<0, 2><<<MT * nb, 256, 0, stream>>>(TxP, Wt, TxQ, Wt + wsl, b2, accb,
                                                   nullptr, N_NODES, NO, F, 0);
    // Tx2 -> TxP, Tx3 -> TxQ
    prop_kernel<1152, 4><<<N_NODES, 320, 0, stream>>>(row_ptr, col_s, w_s, TxQ, TxP, TxP);
    prop_kernel<1152, 4><<<N_NODES, 320, 0, stream>>>(row_ptr, col_s, w_s, TxP, TxQ, TxQ);
    gemm_kernel<1, 2><<<MT * nb, 256, 0, stream>>>(TxP, Wt + 2 * wsl, TxQ, Wt + 3 * wsl,
                                                   b2, accb, nullptr, N_NODES, NO, F, 0);
    // Tx4 -> TxP
    prop_kernel<1152, 4><<<N_NODES, 320, 0, stream>>>(row_ptr, col_s, w_s, TxQ, TxP, TxP);
    // FINAL single (Tx4*W4) -> h2 = TxQ (dead), bf16 ld 576
    gemm_kernel<2, 1><<<MT * nb, 256, 0, stream>>>(TxP, Wt + 4 * wsl, NB, NB, b2, accb,
                                                   TxQ, N_NODES, NO, F, 576);
  }

  // ---------------- layer 3: K=5, 576 -> 288 ----------------
  wtrans_kernel<<<5 * 18 * 9, dim3(32, 8), 0, stream>>>(W3, Wt, 5, 576, 288);
  {
    const int F = 576, NO = 288, nb = 3;
    size_t wsl = (size_t)NO * F;
    // TxQ=h2=Tx0; Tx1 -> TxP
    prop_kernel<576, 2><<<N_NODES, 320, 0, stream>>>(row_ptr, col_s, w_s, TxQ, NB, TxP);
    gemm_kernel<0, 2><<<MT * nb, 256, 0, stream>>>(TxQ, Wt, TxP, Wt + wsl, b3, accb,
                                                   nullptr, N_NODES, NO, F, 0);
    // Tx2 -> TxQ, Tx3 -> TxP
    prop_kernel<576, 2><<<N_NODES, 320, 0, stream>>>(row_ptr, col_s, w_s, TxP, TxQ, TxQ);
    prop_kernel<576, 2><<<N_NODES, 320, 0, stream>>>(row_ptr, col_s, w_s, TxQ, TxP, TxP);
    gemm_kernel<1, 2><<<MT * nb, 256, 0, stream>>>(TxQ, Wt + 2 * wsl, TxP, Wt + 3 * wsl,
                                                   b3, accb, nullptr, N_NODES, NO, F, 0);
    // Tx4 -> TxQ
    prop_kernel<576, 2><<<N_NODES, 320, 0, stream>>>(row_ptr, col_s, w_s, TxP, TxQ, TxQ);
    // FINAL single (Tx4*W4) -> d_out fp32
    gemm_kernel<3, 1><<<MT * nb, 256, 0, stream>>>(TxQ, Wt + 4 * wsl, NB, NB, b3, accb,
                                                   d_out, N_NODES, NO, F, 0);
  }
}

// Round 5
// 2398.437 us; speedup vs baseline: 2.1351x; 1.0480x over previous
//
#include <hip/hip_runtime.h>
#include <hip/hip_bf16.h>

#define N_NODES 20000
#define N_EDGES 320000

typedef __attribute__((ext_vector_type(8))) short shortx8;
typedef __attribute__((ext_vector_type(4))) float floatx4;
using bf16 = __hip_bfloat16;

typedef __attribute__((address_space(1))) const unsigned int GuT;
typedef __attribute__((address_space(3))) unsigned int LuT;
__device__ __forceinline__ void gl2lds16(const bf16* g, bf16* l) {
  // async global->LDS, 16B/lane; LDS dest = wave-uniform base + lane*16
  __builtin_amdgcn_global_load_lds((GuT*)g, (LuT*)l, 16, 0, 0);
}

__device__ inline float b2f(unsigned short u) {
  union { unsigned int i; float f; } x;
  x.i = ((unsigned int)u) << 16;
  return x.f;
}
__device__ inline unsigned short f2b(float f) {
  bf16 h(f);
  return *(unsigned short*)&h;
}

// ---------------- graph prep ----------------

__global__ void zero_kernel(int* p, int n) {
  int i = blockIdx.x * 256 + threadIdx.x;
  if (i < n) p[i] = 0;
}

__global__ void deg_kernel(const int* __restrict__ row, const int* __restrict__ col,
                           int* __restrict__ deg, int nE) {
  int e = blockIdx.x * 256 + threadIdx.x;
  if (e >= nE) return;
  int r = row[e], c = col[e];
  if (r != c) atomicAdd(&deg[r], 1);
}

__global__ void dis_kernel(const int* __restrict__ deg, float* __restrict__ dis, int n) {
  int i = blockIdx.x * 256 + threadIdx.x;
  if (i >= n) return;
  int d = deg[i];
  dis[i] = (d > 0) ? (1.0f / sqrtf((float)d)) : 0.0f;
}

// single-block exclusive scan of deg[0..n) -> row_ptr[0..n], copy to cursor
__global__ __launch_bounds__(1024) void scan_kernel(const int* __restrict__ deg,
                                                    int* __restrict__ row_ptr,
                                                    int* __restrict__ cursor, int n) {
  __shared__ int part[1024];
  int t = threadIdx.x;
  int base = t * 20;
  int loc[20];
  int s = 0;
#pragma unroll
  for (int i = 0; i < 20; i++) {
    int idx = base + i;
    int v = (idx < n) ? deg[idx] : 0;
    loc[i] = s;
    s += v;
  }
  part[t] = s;
  __syncthreads();
  for (int offd = 1; offd < 1024; offd <<= 1) {
    int v = (t >= offd) ? part[t - offd] : 0;
    __syncthreads();
    part[t] += v;
    __syncthreads();
  }
  int basev = (t > 0) ? part[t - 1] : 0;
#pragma unroll
  for (int i = 0; i < 20; i++) {
    int idx = base + i;
    if (idx < n) {
      int rp = basev + loc[i];
      row_ptr[idx] = rp;
      cursor[idx] = rp;
    }
  }
  if (t == 1023) row_ptr[n] = part[1023];
}

__global__ void scatter_kernel(const int* __restrict__ row, const int* __restrict__ col,
                               const float* __restrict__ dis, int* __restrict__ cursor,
                               int* __restrict__ col_s, float* __restrict__ w_s, int nE) {
  int e = blockIdx.x * 256 + threadIdx.x;
  if (e >= nE) return;
  int r = row[e], c = col[e];
  if (r == c) return;
  int p = atomicAdd(&cursor[r], 1);
  col_s[p] = c;
  w_s[p] = -dis[r] * dis[c];
}

// ---------------- weight prep: W (K,I,J) fp32 -> Wt[k][j][i] bf16 ----------------

__global__ void wtrans_kernel(const float* __restrict__ W, bf16* __restrict__ Wt,
                              int K_, int I, int J) {
  __shared__ float tile[32][33];
  int jt = blockIdx.x % (J / 32);
  int rest = blockIdx.x / (J / 32);
  int it = rest % (I / 32);
  int k = rest / (I / 32);
  int tx = threadIdx.x, ty = threadIdx.y;
  const float* src = W + (size_t)k * I * J;
  for (int r = ty; r < 32; r += 8)
    tile[r][tx] = src[(size_t)(it * 32 + r) * J + jt * 32 + tx];
  __syncthreads();
  for (int r = ty; r < 32; r += 8) {
    int j = jt * 32 + r;
    Wt[((size_t)k * J + j) * I + it * 32 + tx] = bf16(tile[tx][r]);
  }
}

// ---------------- cast x (fp32, N x 1152 flat) -> bf16 ----------------

__global__ void cast_x_kernel(const float* __restrict__ x, bf16* __restrict__ dst, int n4) {
  int idx = blockIdx.x * 256 + threadIdx.x;
  if (idx >= n4) return;
  int flat = idx * 4;
  float4 v = *(const float4*)(x + flat);
  dst[flat + 0] = bf16(v.x);
  dst[flat + 1] = bf16(v.y);
  dst[flat + 2] = bf16(v.z);
  dst[flat + 3] = bf16(v.w);
}

// ---------------- prop: dst = L~ src, or dst = 2*L~ src - tx0 (tx0 may alias dst) ----
// 320 threads/block, one block per node; exactly one VEC-chunk per thread (C=288).
// Edge loop unrolled x8 for memory-level parallelism.

template <int F, int VEC>
__global__ __launch_bounds__(320) void prop_kernel(
    const int* __restrict__ row_ptr, const int* __restrict__ col_s,
    const float* __restrict__ w_s, const bf16* __restrict__ src,
    const bf16* tx0, bf16* dst) {
  constexpr int C = F / VEC;  // 288
  int node = blockIdx.x;
  int t = threadIdx.x;
  bool act = t < C;
  int fb = t * VEC;  // feature base for this thread
  int e0 = row_ptr[node], e1 = row_ptr[node + 1];
  float acc[VEC];
#pragma unroll
  for (int q = 0; q < VEC; q++) acc[q] = 0.0f;

  const unsigned short* sp = (const unsigned short*)src;
  int e = e0;
  for (; e + 8 <= e1; e += 8) {
    int cs[8];
    float wv[8];
#pragma unroll
    for (int u = 0; u < 8; u++) {
      cs[u] = col_s[e + u];
      wv[u] = w_s[e + u];
    }
    if (act) {
      if constexpr (VEC == 4) {
        ushort4 v[8];
#pragma unroll
        for (int u = 0; u < 8; u++) v[u] = *(const ushort4*)(sp + (size_t)cs[u] * F + fb);
#pragma unroll
        for (int u = 0; u < 8; u++) {
          acc[0] += wv[u] * b2f(v[u].x);
          acc[1] += wv[u] * b2f(v[u].y);
          acc[2] += wv[u] * b2f(v[u].z);
          acc[3] += wv[u] * b2f(v[u].w);
        }
      } else {
        ushort2 v[8];
#pragma unroll
        for (int u = 0; u < 8; u++) v[u] = *(const ushort2*)(sp + (size_t)cs[u] * F + fb);
#pragma unroll
        for (int u = 0; u < 8; u++) {
          acc[0] += wv[u] * b2f(v[u].x);
          acc[1] += wv[u] * b2f(v[u].y);
        }
      }
    }
  }
  for (; e < e1; e++) {
    int c = col_s[e];
    float w = w_s[e];
    if (act) {
      if constexpr (VEC == 4) {
        ushort4 v = *(const ushort4*)(sp + (size_t)c * F + fb);
        acc[0] += w * b2f(v.x);
        acc[1] += w * b2f(v.y);
        acc[2] += w * b2f(v.z);
        acc[3] += w * b2f(v.w);
      } else {
        ushort2 v = *(const ushort2*)(sp + (size_t)c * F + fb);
        acc[0] += w * b2f(v.x);
        acc[1] += w * b2f(v.y);
      }
    }
  }

  if (!act) return;
  unsigned short* dp = (unsigned short*)dst + (size_t)node * F + fb;
  if (tx0) {
    const unsigned short* t0 = (const unsigned short*)tx0 + (size_t)node * F + fb;
    if constexpr (VEC == 4) {
      ushort4 tv = *(const ushort4*)t0;
      ushort4 o;
      o.x = f2b(2.0f * acc[0] - b2f(tv.x));
      o.y = f2b(2.0f * acc[1] - b2f(tv.y));
      o.z = f2b(2.0f * acc[2] - b2f(tv.z));
      o.w = f2b(2.0f * acc[3] - b2f(tv.w));
      *(ushort4*)dp = o;
    } else {
      ushort2 tv = *(const ushort2*)t0;
      ushort2 o;
      o.x = f2b(2.0f * acc[0] - b2f(tv.x));
      o.y = f2b(2.0f * acc[1] - b2f(tv.y));
      *(ushort2*)dp = o;
    }
  } else {
    if constexpr (VEC == 4) {
      ushort4 o;
      o.x = f2b(acc[0]);
      o.y = f2b(acc[1]);
      o.z = f2b(acc[2]);
      o.w = f2b(acc[3]);
      *(ushort4*)dp = o;
    } else {
      ushort2 o;
      o.x = f2b(acc[0]);
      o.y = f2b(acc[1]);
      *(ushort2*)dp = o;
    }
  }
}

// ---------------- bf16 MFMA GEMM (m97 structure) with K segments + acc modes -------
// XCD-swizzled grid: bid%8 = XCD slot; per-XCD the nb N-tiles of one M-tile run
// consecutively so the A-tile is fetched into that XCD's L2 exactly once.
// Grid must be 8 * ceil(MT/8) * nb blocks (MT = ceil(M/128)).
// MODE 0 (INIT):  accbuf = result + bias     (fp32, stride Nout)
// MODE 1 (ACCUM): accbuf += result
// MODE 2 (FINAL_BF16): dst = relu(accbuf + result) bf16, stride dstLd
// MODE 3 (FINAL_F32):  dst = relu(accbuf + result) fp32, stride Nout

template <int MODE, int NSEG>
__global__ __launch_bounds__(256) void gemm_kernel(
    const bf16* __restrict__ A1, const bf16* __restrict__ B1,
    const bf16* __restrict__ A2, const bf16* __restrict__ B2,
    const float* __restrict__ bias, float* __restrict__ accbuf,
    void* __restrict__ dst, int M, int Nout, int Kt, int dstLd) {
  __shared__ bf16 As[128 * 32];
  __shared__ bf16 Bs[128 * 32];
  int nb = (Nout + 127) >> 7;
  int mtiles = (M + 127) >> 7;
  // XCD swizzle: round-robin bid->XCD; bn fastest within each XCD
  int xcd = blockIdx.x & 7;
  int s = blockIdx.x >> 3;
  int bn = s % nb;
  int bm = (s / nb) * 8 + xcd;
  if (bm >= mtiles) return;
  int m0 = bm << 7, n0 = bn << 7;
  int t = threadIdx.x;
  int lane = t & 63;
  int wave = t >> 6;
  int wm = wave & 1, wn = wave >> 1;
  int l16 = lane & 15;
  int k8 = (lane >> 4) << 3;
  floatx4 acc[4][4] = {};

  // staging geometry: inst covers 16 rows, 4 lanes/row, 8 bf16 (16B) per lane
  int srow = lane >> 2;         // 0..15 within inst
  int scol = (lane & 3) << 3;   // 0,8,16,24

#pragma unroll 1
  for (int seg = 0; seg < NSEG; seg++) {
    const bf16* A = (seg == 0) ? A1 : A2;
    const bf16* Bt = (seg == 0) ? B1 : B2;
#pragma unroll 1
    for (int kt = 0; kt < Kt; kt += 32) {
#pragma unroll
      for (int q = 0; q < 2; q++) {
        int inst = (wave << 1) + q;
        int r = (inst << 4) + srow;
        int ga = m0 + r;
        if (ga < M)
          gl2lds16(A + (size_t)ga * Kt + kt + scol, &As[inst << 9]);
        int gb = n0 + r;
        if (gb < Nout)
          gl2lds16(Bt + (size_t)gb * Kt + kt + scol, &Bs[inst << 9]);
      }
      __syncthreads();
      shortx8 af[4], bfr[4];
#pragma unroll
      for (int i = 0; i < 4; i++)
        af[i] = *(const shortx8*)&As[(((wm << 6) + (i << 4) + l16) << 5) + k8];
#pragma unroll
      for (int j = 0; j < 4; j++)
        bfr[j] = *(const shortx8*)&Bs[(((wn << 6) + (j << 4) + l16) << 5) + k8];
#pragma unroll
      for (int i = 0; i < 4; i++)
#pragma unroll
        for (int j = 0; j < 4; j++)
          acc[i][j] = __builtin_amdgcn_mfma_f32_16x16x32_bf16(af[i], bfr[j], acc[i][j], 0, 0, 0);
      __syncthreads();
    }
  }

  // epilogue: C/D layout col = lane&15, row = (lane>>4)*4 + reg
  int lq = lane >> 4;
#pragma unroll
  for (int j = 0; j < 4; j++) {
    int colg = n0 + (wn << 6) + (j << 4) + l16;
    if (colg >= Nout) continue;
    float bv = (MODE == 0) ? bias[colg] : 0.0f;
#pragma unroll
    for (int i = 0; i < 4; i++) {
      int rowb = m0 + (wm << 6) + (i << 4) + (lq << 2);
#pragma unroll
      for (int q = 0; q < 4; q++) {
        int rowg = rowb + q;
        if (rowg >= M) continue;
        float v = acc[i][j][q];
        size_t aidx = (size_t)rowg * Nout + colg;
        if constexpr (MODE == 0) {
          accbuf[aidx] = v + bv;
        } else if constexpr (MODE == 1) {
          accbuf[aidx] += v;
        } else if constexpr (MODE == 2) {
          float s2 = fmaxf(accbuf[aidx] + v, 0.0f);
          ((bf16*)dst)[(size_t)rowg * dstLd + colg] = bf16(s2);
        } else {
          float s2 = fmaxf(accbuf[aidx] + v, 0.0f);
          ((float*)dst)[(size_t)rowg * Nout + colg] = s2;
        }
      }
    }
  }
}

// ---------------- host launch ----------------

extern "C" void kernel_launch(void* const* d_in, const int* in_sizes, int n_in,
                              void* d_out, int out_size, void* d_ws, size_t ws_size,
                              hipStream_t stream) {
  const float* x = (const float*)d_in[0];
  const int* row = (const int*)d_in[1];
  const int* col = (const int*)d_in[2];
  const float* W1 = (const float*)d_in[3];
  const float* b1 = (const float*)d_in[4];
  const float* W2 = (const float*)d_in[5];
  const float* b2 = (const float*)d_in[6];
  const float* W3 = (const float*)d_in[7];
  const float* b3 = (const float*)d_in[8];

  char* ws = (char*)d_ws;
  size_t off = 0;
  auto alloc = [&](size_t bytes) -> void* {
    void* p = ws + off;
    off += (bytes + 255) & ~(size_t)255;
    return p;
  };

  // ~194 MiB total (known to fit)
  bf16* Wt = (bf16*)alloc((size_t)6 * 1152 * 1152 * 2);  // reused per layer
  int* deg = (int*)alloc(N_NODES * 4);
  float* dis = (float*)alloc(N_NODES * 4);
  int* row_ptr = (int*)alloc((N_NODES + 1) * 4);
  int* cursor = (int*)alloc(N_NODES * 4);
  int* col_s = (int*)alloc(N_EDGES * 4);
  float* w_s = (float*)alloc(N_EDGES * 4);
  bf16* TxP = (bf16*)alloc((size_t)N_NODES * 1152 * 2);
  bf16* TxQ = (bf16*)alloc((size_t)N_NODES * 1152 * 2);
  float* accb = (float*)alloc((size_t)N_NODES * 1152 * 4);
  if (off > ws_size) return;  // workspace too small -> validation fails loudly

  // graph prep
  zero_kernel<<<(N_NODES + 255) / 256, 256, 0, stream>>>(deg, N_NODES);
  deg_kernel<<<(N_EDGES + 255) / 256, 256, 0, stream>>>(row, col, deg, N_EDGES);
  dis_kernel<<<(N_NODES + 255) / 256, 256, 0, stream>>>(deg, dis, N_NODES);
  scan_kernel<<<1, 1024, 0, stream>>>(deg, row_ptr, cursor, N_NODES);
  scatter_kernel<<<(N_EDGES + 255) / 256, 256, 0, stream>>>(row, col, dis, cursor,
                                                            col_s, w_s, N_EDGES);

  const int MT = (N_NODES + 127) >> 7;        // 157 M-tiles
  const int GMT = 8 * ((MT + 7) >> 3);        // 160, XCD-padded
  const bf16* NB = nullptr;

  // ---------------- layer 1: K=6, 1152 -> 1152 ----------------
  wtrans_kernel<<<6 * 36 * 36, dim3(32, 8), 0, stream>>>(W1, Wt, 6, 1152, 1152);
  cast_x_kernel<<<(N_NODES * 1152 / 4 + 255) / 256, 256, 0, stream>>>(x, TxP,
                                                                      N_NODES * 1152 / 4);
  {
    const int F = 1152, NO = 1152, nb = 9;
    size_t wsl = (size_t)NO * F;
    // TxP=Tx0; Tx1 -> TxQ
    prop_kernel<1152, 4><<<N_NODES, 320, 0, stream>>>(row_ptr, col_s, w_s, TxP, NB, TxQ);
    // INIT pair (Tx0*W0 + Tx1*W1 + b)
    gemm_kernel<0, 2><<<GMT * nb, 256, 0, stream>>>(TxP, Wt, TxQ, Wt + wsl, b1, accb,
                                                    nullptr, N_NODES, NO, F, 0);
    // Tx2 -> TxP, Tx3 -> TxQ
    prop_kernel<1152, 4><<<N_NODES, 320, 0, stream>>>(row_ptr, col_s, w_s, TxQ, TxP, TxP);
    prop_kernel<1152, 4><<<N_NODES, 320, 0, stream>>>(row_ptr, col_s, w_s, TxP, TxQ, TxQ);
    // ACCUM pair (Tx2*W2 + Tx3*W3)
    gemm_kernel<1, 2><<<GMT * nb, 256, 0, stream>>>(TxP, Wt + 2 * wsl, TxQ, Wt + 3 * wsl,
                                                    b1, accb, nullptr, N_NODES, NO, F, 0);
    // Tx4 -> TxP, Tx5 -> TxQ
    prop_kernel<1152, 4><<<N_NODES, 320, 0, stream>>>(row_ptr, col_s, w_s, TxQ, TxP, TxP);
    prop_kernel<1152, 4><<<N_NODES, 320, 0, stream>>>(row_ptr, col_s, w_s, TxP, TxQ, TxQ);
    // ACCUM single (Tx4*W4)
    gemm_kernel<1, 1><<<GMT * nb, 256, 0, stream>>>(TxP, Wt + 4 * wsl, NB, NB, b1, accb,
                                                    nullptr, N_NODES, NO, F, 0);
    // FINAL single (Tx5*W5) -> h1 = TxP (dead), bf16 ld 1152
    gemm_kernel<2, 1><<<GMT * nb, 256, 0, stream>>>(TxQ, Wt + 5 * wsl, NB, NB, b1, accb,
                                                    TxP, N_NODES, NO, F, 1152);
  }

  // ---------------- layer 2: K=5, 1152 -> 576 ----------------
  wtrans_kernel<<<5 * 36 * 18, dim3(32, 8), 0, stream>>>(W2, Wt, 5, 1152, 576);
  {
    const int F = 1152, NO = 576, nb = 5;
    size_t wsl = (size_t)NO * F;
    // TxP=h1=Tx0; Tx1 -> TxQ
    prop_kernel<1152, 4><<<N_NODES, 320, 0, stream>>>(row_ptr, col_s, w_s, TxP, NB, TxQ);
    gemm_kernel<0, 2><<<GMT * nb, 256, 0, stream>>>(TxP, Wt, TxQ, Wt + wsl, b2, accb,
                                                    nullptr, N_NODES, NO, F, 0);
    // Tx2 -> TxP, Tx3 -> TxQ
    prop_kernel<1152, 4><<<N_NODES, 320, 0, stream>>>(row_ptr, col_s, w_s, TxQ, TxP, TxP);
    prop_kernel<1152, 4><<<N_NODES, 320, 0, stream>>>(row_ptr, col_s, w_s, TxP, TxQ, TxQ);
    gemm_kernel<1, 2><<<GMT * nb, 256, 0, stream>>>(TxP, Wt + 2 * wsl, TxQ, Wt + 3 * wsl,
                                                    b2, accb, nullptr, N_NODES, NO, F, 0);
    // Tx4 -> TxP
    prop_kernel<1152, 4><<<N_NODES, 320, 0, stream>>>(row_ptr, col_s, w_s, TxQ, TxP, TxP);
    // FINAL single (Tx4*W4) -> h2 = TxQ (dead), bf16 ld 576
    gemm_kernel<2, 1><<<GMT * nb, 256, 0, stream>>>(TxP, Wt + 4 * wsl, NB, NB, b2, accb,
                                                    TxQ, N_NODES, NO, F, 576);
  }

  // ---------------- layer 3: K=5, 576 -> 288 ----------------
  wtrans_kernel<<<5 * 18 * 9, dim3(32, 8), 0, stream>>>(W3, Wt, 5, 576, 288);
  {
    const int F = 576, NO = 288, nb = 3;
    size_t wsl = (size_t)NO * F;
    // TxQ=h2=Tx0; Tx1 -> TxP
    prop_kernel<576, 2><<<N_NODES, 320, 0, stream>>>(row_ptr, col_s, w_s, TxQ, NB, TxP);
    gemm_kernel<0, 2><<<GMT * nb, 256, 0, stream>>>(TxQ, Wt, TxP, Wt + wsl, b3, accb,
                                                    nullptr, N_NODES, NO, F, 0);
    // Tx2 -> TxQ, Tx3 -> TxP
    prop_kernel<576, 2><<<N_NODES, 320, 0, stream>>>(row_ptr, col_s, w_s, TxP, TxQ, TxQ);
    prop_kernel<576, 2><<<N_NODES, 320, 0, stream>>>(row_ptr, col_s, w_s, TxQ, TxP, TxP);
    gemm_kernel<1, 2><<<GMT * nb, 256, 0, stream>>>(TxQ, Wt + 2 * wsl, TxP, Wt + 3 * wsl,
                                                    b3, accb, nullptr, N_NODES, NO, F, 0);
    // Tx4 -> TxQ
    prop_kernel<576, 2><<<N_NODES, 320, 0, stream>>>(row_ptr, col_s, w_s, TxP, TxQ, TxQ);
    // FINAL single (Tx4*W4) -> d_out fp32
    gemm_kernel<3, 1><<<GMT * nb, 256, 0, stream>>>(TxQ, Wt + 4 * wsl, NB, NB, b3, accb,
                                                    d_out, N_NODES, NO, F, 0);
  }
}

// Round 6
// 2135.714 us; speedup vs baseline: 2.3977x; 1.1230x over previous
//
#include <hip/hip_runtime.h>
#include <hip/hip_bf16.h>

#define N_NODES 20000
#define N_EDGES 320000

typedef __attribute__((ext_vector_type(8))) short shortx8;
typedef __attribute__((ext_vector_type(4))) float floatx4;
using bf16 = __hip_bfloat16;

typedef __attribute__((address_space(1))) const unsigned int GuT;
typedef __attribute__((address_space(3))) unsigned int LuT;
__device__ __forceinline__ void gl2lds16(const bf16* g, bf16* l) {
  // async global->LDS, 16B/lane; LDS dest = wave-uniform base + lane*16
  __builtin_amdgcn_global_load_lds((GuT*)g, (LuT*)l, 16, 0, 0);
}

__device__ inline float b2f(unsigned short u) {
  union { unsigned int i; float f; } x;
  x.i = ((unsigned int)u) << 16;
  return x.f;
}
__device__ inline unsigned short f2b(float f) {
  bf16 h(f);
  return *(unsigned short*)&h;
}

struct APtrs { const bf16* p[6]; };

// ---------------- graph prep ----------------

__global__ void zero_kernel(int* p, int n) {
  int i = blockIdx.x * 256 + threadIdx.x;
  if (i < n) p[i] = 0;
}

__global__ void deg_kernel(const int* __restrict__ row, const int* __restrict__ col,
                           int* __restrict__ deg, int nE) {
  int e = blockIdx.x * 256 + threadIdx.x;
  if (e >= nE) return;
  int r = row[e], c = col[e];
  if (r != c) atomicAdd(&deg[r], 1);
}

__global__ void dis_kernel(const int* __restrict__ deg, float* __restrict__ dis, int n) {
  int i = blockIdx.x * 256 + threadIdx.x;
  if (i >= n) return;
  int d = deg[i];
  dis[i] = (d > 0) ? (1.0f / sqrtf((float)d)) : 0.0f;
}

__global__ __launch_bounds__(1024) void scan_kernel(const int* __restrict__ deg,
                                                    int* __restrict__ row_ptr,
                                                    int* __restrict__ cursor, int n) {
  __shared__ int part[1024];
  int t = threadIdx.x;
  int base = t * 20;
  int loc[20];
  int s = 0;
#pragma unroll
  for (int i = 0; i < 20; i++) {
    int idx = base + i;
    int v = (idx < n) ? deg[idx] : 0;
    loc[i] = s;
    s += v;
  }
  part[t] = s;
  __syncthreads();
  for (int offd = 1; offd < 1024; offd <<= 1) {
    int v = (t >= offd) ? part[t - offd] : 0;
    __syncthreads();
    part[t] += v;
    __syncthreads();
  }
  int basev = (t > 0) ? part[t - 1] : 0;
#pragma unroll
  for (int i = 0; i < 20; i++) {
    int idx = base + i;
    if (idx < n) {
      int rp = basev + loc[i];
      row_ptr[idx] = rp;
      cursor[idx] = rp;
    }
  }
  if (t == 1023) row_ptr[n] = part[1023];
}

__global__ void scatter_kernel(const int* __restrict__ row, const int* __restrict__ col,
                               const float* __restrict__ dis, int* __restrict__ cursor,
                               int* __restrict__ col_s, float* __restrict__ w_s, int nE) {
  int e = blockIdx.x * 256 + threadIdx.x;
  if (e >= nE) return;
  int r = row[e], c = col[e];
  if (r == c) return;
  int p = atomicAdd(&cursor[r], 1);
  col_s[p] = c;
  w_s[p] = -dis[r] * dis[c];
}

// ---------------- weight prep: W (K,I,J) fp32 -> Wt[k][j][i] bf16 ----------------

__global__ void wtrans_kernel(const float* __restrict__ W, bf16* __restrict__ Wt,
                              int K_, int I, int J) {
  __shared__ float tile[32][33];
  int jt = blockIdx.x % (J / 32);
  int rest = blockIdx.x / (J / 32);
  int it = rest % (I / 32);
  int k = rest / (I / 32);
  int tx = threadIdx.x, ty = threadIdx.y;
  const float* src = W + (size_t)k * I * J;
  for (int r = ty; r < 32; r += 8)
    tile[r][tx] = src[(size_t)(it * 32 + r) * J + jt * 32 + tx];
  __syncthreads();
  for (int r = ty; r < 32; r += 8) {
    int j = jt * 32 + r;
    Wt[((size_t)k * J + j) * I + it * 32 + tx] = bf16(tile[tx][r]);
  }
}

// ---------------- cast x (fp32 flat) -> bf16 ----------------

__global__ void cast_x_kernel(const float* __restrict__ x, bf16* __restrict__ dst, int n4) {
  int idx = blockIdx.x * 256 + threadIdx.x;
  if (idx >= n4) return;
  int flat = idx * 4;
  float4 v = *(const float4*)(x + flat);
  dst[flat + 0] = bf16(v.x);
  dst[flat + 1] = bf16(v.y);
  dst[flat + 2] = bf16(v.z);
  dst[flat + 3] = bf16(v.w);
}

// ---------------- prop: dst = L~ src, or dst = 2*L~ src - tx0 (tx0 may alias dst) ----
// 320 threads/block, one block per node; one VEC-chunk per thread (C=288 active).
// Edge loop unrolled x16 (avg degree 16) for memory-level parallelism; x4 + scalar tails.

template <int F, int VEC>
__global__ __launch_bounds__(320) void prop_kernel(
    const int* __restrict__ row_ptr, const int* __restrict__ col_s,
    const float* __restrict__ w_s, const bf16* __restrict__ src,
    const bf16* tx0, bf16* dst) {
  constexpr int C = F / VEC;  // 288
  int node = blockIdx.x;
  int t = threadIdx.x;
  bool act = t < C;
  int fb = t * VEC;
  int e0 = row_ptr[node], e1 = row_ptr[node + 1];
  float acc[VEC];
#pragma unroll
  for (int q = 0; q < VEC; q++) acc[q] = 0.0f;

  const unsigned short* sp = (const unsigned short*)src;
  int e = e0;
  for (; e + 16 <= e1; e += 16) {
    int cs[16];
    float wv[16];
#pragma unroll
    for (int u = 0; u < 16; u++) {
      cs[u] = col_s[e + u];
      wv[u] = w_s[e + u];
    }
    if (act) {
      if constexpr (VEC == 4) {
        ushort4 v[16];
#pragma unroll
        for (int u = 0; u < 16; u++) v[u] = *(const ushort4*)(sp + (size_t)cs[u] * F + fb);
#pragma unroll
        for (int u = 0; u < 16; u++) {
          acc[0] += wv[u] * b2f(v[u].x);
          acc[1] += wv[u] * b2f(v[u].y);
          acc[2] += wv[u] * b2f(v[u].z);
          acc[3] += wv[u] * b2f(v[u].w);
        }
      } else {
        ushort2 v[16];
#pragma unroll
        for (int u = 0; u < 16; u++) v[u] = *(const ushort2*)(sp + (size_t)cs[u] * F + fb);
#pragma unroll
        for (int u = 0; u < 16; u++) {
          acc[0] += wv[u] * b2f(v[u].x);
          acc[1] += wv[u] * b2f(v[u].y);
        }
      }
    }
  }
  for (; e + 4 <= e1; e += 4) {
    int cs[4];
    float wv[4];
#pragma unroll
    for (int u = 0; u < 4; u++) {
      cs[u] = col_s[e + u];
      wv[u] = w_s[e + u];
    }
    if (act) {
      if constexpr (VEC == 4) {
        ushort4 v[4];
#pragma unroll
        for (int u = 0; u < 4; u++) v[u] = *(const ushort4*)(sp + (size_t)cs[u] * F + fb);
#pragma unroll
        for (int u = 0; u < 4; u++) {
          acc[0] += wv[u] * b2f(v[u].x);
          acc[1] += wv[u] * b2f(v[u].y);
          acc[2] += wv[u] * b2f(v[u].z);
          acc[3] += wv[u] * b2f(v[u].w);
        }
      } else {
        ushort2 v[4];
#pragma unroll
        for (int u = 0; u < 4; u++) v[u] = *(const ushort2*)(sp + (size_t)cs[u] * F + fb);
#pragma unroll
        for (int u = 0; u < 4; u++) {
          acc[0] += wv[u] * b2f(v[u].x);
          acc[1] += wv[u] * b2f(v[u].y);
        }
      }
    }
  }
  for (; e < e1; e++) {
    int c = col_s[e];
    float w = w_s[e];
    if (act) {
      if constexpr (VEC == 4) {
        ushort4 v = *(const ushort4*)(sp + (size_t)c * F + fb);
        acc[0] += w * b2f(v.x);
        acc[1] += w * b2f(v.y);
        acc[2] += w * b2f(v.z);
        acc[3] += w * b2f(v.w);
      } else {
        ushort2 v = *(const ushort2*)(sp + (size_t)c * F + fb);
        acc[0] += w * b2f(v.x);
        acc[1] += w * b2f(v.y);
      }
    }
  }

  if (!act) return;
  unsigned short* dp = (unsigned short*)dst + (size_t)node * F + fb;
  if (tx0) {
    const unsigned short* t0 = (const unsigned short*)tx0 + (size_t)node * F + fb;
    if constexpr (VEC == 4) {
      ushort4 tv = *(const ushort4*)t0;
      ushort4 o;
      o.x = f2b(2.0f * acc[0] - b2f(tv.x));
      o.y = f2b(2.0f * acc[1] - b2f(tv.y));
      o.z = f2b(2.0f * acc[2] - b2f(tv.z));
      o.w = f2b(2.0f * acc[3] - b2f(tv.w));
      *(ushort4*)dp = o;
    } else {
      ushort2 tv = *(const ushort2*)t0;
      ushort2 o;
      o.x = f2b(2.0f * acc[0] - b2f(tv.x));
      o.y = f2b(2.0f * acc[1] - b2f(tv.y));
      *(ushort2*)dp = o;
    }
  } else {
    if constexpr (VEC == 4) {
      ushort4 o;
      o.x = f2b(acc[0]);
      o.y = f2b(acc[1]);
      o.z = f2b(acc[2]);
      o.w = f2b(acc[3]);
      *(ushort4*)dp = o;
    } else {
      ushort2 o;
      o.x = f2b(acc[0]);
      o.y = f2b(acc[1]);
      *(ushort2*)dp = o;
    }
  }
}

// ---------------- bf16 MFMA GEMM (m97 structure), multi-segment, XCD-swizzled ------
// result = sum_s A_s @ B_s^T, B_s = Bbase + s*Nout*Kt (contiguous weight slices).
// MODE 0: accbuf = result + bias   MODE 1: accbuf += result
// MODE 2: dst = relu(accbuf+result) bf16 ld  MODE 3: dst = relu(accbuf+result) f32
// MODE 4: dst = relu(result+bias) bf16 ld    MODE 5: dst = relu(result+bias) f32

template <int MODE, int NSEG>
__global__ __launch_bounds__(256) void gemm_kernel(
    APtrs ap, const bf16* __restrict__ Bbase,
    const float* __restrict__ bias, float* __restrict__ accbuf,
    void* __restrict__ dst, int M, int Nout, int Kt, int dstLd) {
  __shared__ bf16 As[128 * 32];
  __shared__ bf16 Bs[128 * 32];
  int nb = (Nout + 127) >> 7;
  int mtiles = (M + 127) >> 7;
  int xcd = blockIdx.x & 7;
  int s = blockIdx.x >> 3;
  int bn = s % nb;
  int bm = (s / nb) * 8 + xcd;
  if (bm >= mtiles) return;
  int m0 = bm << 7, n0 = bn << 7;
  int t = threadIdx.x;
  int lane = t & 63;
  int wave = t >> 6;
  int wm = wave & 1, wn = wave >> 1;
  int l16 = lane & 15;
  int k8 = (lane >> 4) << 3;
  floatx4 acc[4][4] = {};

  int srow = lane >> 2;        // 0..15 within a 16-row staging inst
  int scol = (lane & 3) << 3;  // 0,8,16,24

#pragma unroll
  for (int seg = 0; seg < NSEG; seg++) {
    const bf16* A = ap.p[seg];
    const bf16* Bt = Bbase + (size_t)seg * Nout * Kt;
#pragma unroll 1
    for (int kt = 0; kt < Kt; kt += 32) {
#pragma unroll
      for (int q = 0; q < 2; q++) {
        int inst = (wave << 1) + q;
        int r = (inst << 4) + srow;
        int ga = m0 + r;
        if (ga < M)
          gl2lds16(A + (size_t)ga * Kt + kt + scol, &As[inst << 9]);
        int gb = n0 + r;
        if (gb < Nout)
          gl2lds16(Bt + (size_t)gb * Kt + kt + scol, &Bs[inst << 9]);
      }
      __syncthreads();
      shortx8 af[4], bfr[4];
#pragma unroll
      for (int i = 0; i < 4; i++)
        af[i] = *(const shortx8*)&As[(((wm << 6) + (i << 4) + l16) << 5) + k8];
#pragma unroll
      for (int j = 0; j < 4; j++)
        bfr[j] = *(const shortx8*)&Bs[(((wn << 6) + (j << 4) + l16) << 5) + k8];
#pragma unroll
      for (int i = 0; i < 4; i++)
#pragma unroll
        for (int j = 0; j < 4; j++)
          acc[i][j] = __builtin_amdgcn_mfma_f32_16x16x32_bf16(af[i], bfr[j], acc[i][j], 0, 0, 0);
      __syncthreads();
    }
  }

  // epilogue: C/D layout col = lane&15, row = (lane>>4)*4 + reg
  int lq = lane >> 4;
#pragma unroll
  for (int j = 0; j < 4; j++) {
    int colg = n0 + (wn << 6) + (j << 4) + l16;
    if (colg >= Nout) continue;
    float bv = (MODE == 0 || MODE == 4 || MODE == 5) ? bias[colg] : 0.0f;
#pragma unroll
    for (int i = 0; i < 4; i++) {
      int rowb = m0 + (wm << 6) + (i << 4) + (lq << 2);
#pragma unroll
      for (int q = 0; q < 4; q++) {
        int rowg = rowb + q;
        if (rowg >= M) continue;
        float v = acc[i][j][q];
        size_t aidx = (size_t)rowg * Nout + colg;
        if constexpr (MODE == 0) {
          accbuf[aidx] = v + bv;
        } else if constexpr (MODE == 1) {
          accbuf[aidx] += v;
        } else if constexpr (MODE == 2) {
          float s2 = fmaxf(accbuf[aidx] + v, 0.0f);
          ((bf16*)dst)[(size_t)rowg * dstLd + colg] = bf16(s2);
        } else if constexpr (MODE == 3) {
          float s2 = fmaxf(accbuf[aidx] + v, 0.0f);
          ((float*)dst)[(size_t)rowg * Nout + colg] = s2;
        } else if constexpr (MODE == 4) {
          float s2 = fmaxf(v + bv, 0.0f);
          ((bf16*)dst)[(size_t)rowg * dstLd + colg] = bf16(s2);
        } else {
          float s2 = fmaxf(v + bv, 0.0f);
          ((float*)dst)[(size_t)rowg * Nout + colg] = s2;
        }
      }
    }
  }
}

// ---------------- host launch ----------------

extern "C" void kernel_launch(void* const* d_in, const int* in_sizes, int n_in,
                              void* d_out, int out_size, void* d_ws, size_t ws_size,
                              hipStream_t stream) {
  const float* x = (const float*)d_in[0];
  const int* row = (const int*)d_in[1];
  const int* col = (const int*)d_in[2];
  const float* W1 = (const float*)d_in[3];
  const float* b1 = (const float*)d_in[4];
  const float* W2 = (const float*)d_in[5];
  const float* b2 = (const float*)d_in[6];
  const float* W3 = (const float*)d_in[7];
  const float* b3 = (const float*)d_in[8];

  char* ws = (char*)d_ws;
  size_t off = 0;
  auto alloc = [&](size_t bytes) -> void* {
    void* p = ws + off;
    off += (bytes + 255) & ~(size_t)255;
    return p;
  };

  const size_t TXB = (size_t)N_NODES * 1152 * 2;  // 46.08 MB
  // common: Wt + graph
  bf16* Wt = (bf16*)alloc((size_t)6 * 1152 * 1152 * 2);
  int* deg = (int*)alloc(N_NODES * 4);
  float* dis = (float*)alloc(N_NODES * 4);
  int* row_ptr = (int*)alloc((N_NODES + 1) * 4);
  int* cursor = (int*)alloc(N_NODES * 4);
  int* col_s = (int*)alloc(N_EDGES * 4);
  float* w_s = (float*)alloc(N_EDGES * 4);
  size_t off_common = off;

  // tier gates (A: 7 Tx bufs, no acc; B: 3 Tx + acc; C: 2 Tx + acc)
  size_t need_A = off_common + 7 * ((TXB + 255) & ~(size_t)255);
  size_t need_B = off_common + 3 * ((TXB + 255) & ~(size_t)255) +
                  (((size_t)N_NODES * 1152 * 4 + 255) & ~(size_t)255);
  int tier = (ws_size >= need_A) ? 0 : (ws_size >= need_B) ? 1 : 2;

  // graph prep (all tiers)
  zero_kernel<<<(N_NODES + 255) / 256, 256, 0, stream>>>(deg, N_NODES);
  deg_kernel<<<(N_EDGES + 255) / 256, 256, 0, stream>>>(row, col, deg, N_EDGES);
  dis_kernel<<<(N_NODES + 255) / 256, 256, 0, stream>>>(deg, dis, N_NODES);
  scan_kernel<<<1, 1024, 0, stream>>>(deg, row_ptr, cursor, N_NODES);
  scatter_kernel<<<(N_EDGES + 255) / 256, 256, 0, stream>>>(row, col, dis, cursor,
                                                            col_s, w_s, N_EDGES);

  const int MT = (N_NODES + 127) >> 7;
  const int GMT = 8 * ((MT + 7) >> 3);  // 160
  const bf16* NB = nullptr;
  const int NX = N_NODES * 1152 / 4;

  if (tier == 0) {
    // ================= Tier A: batched-K, no accumulator =================
    bf16* T[7];
    for (int i = 0; i < 7; i++) T[i] = (bf16*)alloc(TXB);

    // layer 1: K=6, 1152 -> 1152
    wtrans_kernel<<<6 * 36 * 36, dim3(32, 8), 0, stream>>>(W1, Wt, 6, 1152, 1152);
    cast_x_kernel<<<(NX + 255) / 256, 256, 0, stream>>>(x, T[0], NX);
    prop_kernel<1152, 4><<<N_NODES, 320, 0, stream>>>(row_ptr, col_s, w_s, T[0], NB, T[1]);
    prop_kernel<1152, 4><<<N_NODES, 320, 0, stream>>>(row_ptr, col_s, w_s, T[1], T[0], T[2]);
    prop_kernel<1152, 4><<<N_NODES, 320, 0, stream>>>(row_ptr, col_s, w_s, T[2], T[1], T[3]);
    prop_kernel<1152, 4><<<N_NODES, 320, 0, stream>>>(row_ptr, col_s, w_s, T[3], T[2], T[4]);
    prop_kernel<1152, 4><<<N_NODES, 320, 0, stream>>>(row_ptr, col_s, w_s, T[4], T[3], T[5]);
    {
      APtrs a = {{T[0], T[1], T[2], T[3], T[4], T[5]}};
      gemm_kernel<4, 6><<<GMT * 9, 256, 0, stream>>>(a, Wt, b1, nullptr, T[6],
                                                     N_NODES, 1152, 1152, 1152);
    }

    // layer 2: K=5, 1152 -> 576 ; h1 = T[6]
    wtrans_kernel<<<5 * 36 * 18, dim3(32, 8), 0, stream>>>(W2, Wt, 5, 1152, 576);
    prop_kernel<1152, 4><<<N_NODES, 320, 0, stream>>>(row_ptr, col_s, w_s, T[6], NB, T[0]);
    prop_kernel<1152, 4><<<N_NODES, 320, 0, stream>>>(row_ptr, col_s, w_s, T[0], T[6], T[1]);
    prop_kernel<1152, 4><<<N_NODES, 320, 0, stream>>>(row_ptr, col_s, w_s, T[1], T[0], T[2]);
    prop_kernel<1152, 4><<<N_NODES, 320, 0, stream>>>(row_ptr, col_s, w_s, T[2], T[1], T[3]);
    {
      APtrs a = {{T[6], T[0], T[1], T[2], T[3], nullptr}};
      gemm_kernel<4, 5><<<GMT * 5, 256, 0, stream>>>(a, Wt, b2, nullptr, T[4],
                                                     N_NODES, 576, 1152, 576);
    }

    // layer 3: K=5, 576 -> 288 ; h2 = T[4]
    wtrans_kernel<<<5 * 18 * 9, dim3(32, 8), 0, stream>>>(W3, Wt, 5, 576, 288);
    prop_kernel<576, 2><<<N_NODES, 320, 0, stream>>>(row_ptr, col_s, w_s, T[4], NB, T[5]);
    prop_kernel<576, 2><<<N_NODES, 320, 0, stream>>>(row_ptr, col_s, w_s, T[5], T[4], T[0]);
    prop_kernel<576, 2><<<N_NODES, 320, 0, stream>>>(row_ptr, col_s, w_s, T[0], T[5], T[1]);
    prop_kernel<576, 2><<<N_NODES, 320, 0, stream>>>(row_ptr, col_s, w_s, T[1], T[0], T[2]);
    {
      APtrs a = {{T[4], T[5], T[0], T[1], T[2], nullptr}};
      gemm_kernel<5, 5><<<GMT * 3, 256, 0, stream>>>(a, Wt, b3, nullptr, d_out,
                                                     N_NODES, 288, 576, 0);
    }
    return;
  }

  // ================= Tiers B/C: rolling buffers + fp32 accbuf =================
  bf16* TxP = (bf16*)alloc(TXB);
  bf16* TxQ = (bf16*)alloc(TXB);
  bf16* Th = (tier == 1) ? (bf16*)alloc(TXB) : nullptr;
  float* accb = (float*)alloc((size_t)N_NODES * 1152 * 4);
  if (off > ws_size) return;

  // layer 1: K=6, 1152 -> 1152
  wtrans_kernel<<<6 * 36 * 36, dim3(32, 8), 0, stream>>>(W1, Wt, 6, 1152, 1152);
  cast_x_kernel<<<(NX + 255) / 256, 256, 0, stream>>>(x, TxP, NX);
  {
    const int F = 1152, NO = 1152, nb = 9;
    size_t wsl = (size_t)NO * F;
    prop_kernel<1152, 4><<<N_NODES, 320, 0, stream>>>(row_ptr, col_s, w_s, TxP, NB, TxQ);
    APtrs a01 = {{TxP, TxQ}};
    gemm_kernel<0, 2><<<GMT * nb, 256, 0, stream>>>(a01, Wt, b1, accb, nullptr,
                                                    N_NODES, NO, F, 0);
    prop_kernel<1152, 4><<<N_NODES, 320, 0, stream>>>(row_ptr, col_s, w_s, TxQ, TxP, TxP);
    prop_kernel<1152, 4><<<N_NODES, 320, 0, stream>>>(row_ptr, col_s, w_s, TxP, TxQ, TxQ);
    APtrs a23 = {{TxP, TxQ}};
    gemm_kernel<1, 2><<<GMT * nb, 256, 0, stream>>>(a23, Wt + 2 * wsl, b1, accb, nullptr,
                                                    N_NODES, NO, F, 0);
    prop_kernel<1152, 4><<<N_NODES, 320, 0, stream>>>(row_ptr, col_s, w_s, TxQ, TxP, TxP);
    prop_kernel<1152, 4><<<N_NODES, 320, 0, stream>>>(row_ptr, col_s, w_s, TxP, TxQ, TxQ);
    if (tier == 1) {
      // FINAL pair (Tx4=TxP, Tx5=TxQ) -> h1 = Th
      APtrs a45 = {{TxP, TxQ}};
      gemm_kernel<2, 2><<<GMT * nb, 256, 0, stream>>>(a45, Wt + 4 * wsl, b1, accb, Th,
                                                      N_NODES, NO, F, 1152);
    } else {
      APtrs a4 = {{TxP}};
      gemm_kernel<1, 1><<<GMT * nb, 256, 0, stream>>>(a4, Wt + 4 * wsl, b1, accb, nullptr,
                                                      N_NODES, NO, F, 0);
      APtrs a5 = {{TxQ}};
      gemm_kernel<2, 1><<<GMT * nb, 256, 0, stream>>>(a5, Wt + 5 * wsl, b1, accb, TxP,
                                                      N_NODES, NO, F, 1152);
    }
  }

  bf16* h1 = (tier == 1) ? Th : TxP;   // layer-2 Tx0
  bf16* u0 = (tier == 1) ? TxP : TxQ;  // free rolling buffers
  bf16* u1 = (tier == 1) ? TxQ : TxP;  // (u1 aliases h1 in tier C only after it's dead)

  // layer 2: K=5, 1152 -> 576
  wtrans_kernel<<<5 * 36 * 18, dim3(32, 8), 0, stream>>>(W2, Wt, 5, 1152, 576);
  {
    const int F = 1152, NO = 576, nb = 5;
    size_t wsl = (size_t)NO * F;
    prop_kernel<1152, 4><<<N_NODES, 320, 0, stream>>>(row_ptr, col_s, w_s, h1, NB, u0);
    APtrs a01 = {{h1, u0}};
    gemm_kernel<0, 2><<<GMT * nb, 256, 0, stream>>>(a01, Wt, b2, accb, nullptr,
                                                    N_NODES, NO, F, 0);
    // Tx2 = 2L~Tx1 - Tx0 -> overwrite h1's buffer (dead after INIT)
    prop_kernel<1152, 4><<<N_NODES, 320, 0, stream>>>(row_ptr, col_s, w_s, u0, h1, h1);
    prop_kernel<1152, 4><<<N_NODES, 320, 0, stream>>>(row_ptr, col_s, w_s, h1, u0, u0);
    APtrs a23 = {{h1, u0}};
    gemm_kernel<1, 2><<<GMT * nb, 256, 0, stream>>>(a23, Wt + 2 * wsl, b2, accb, nullptr,
                                                    N_NODES, NO, F, 0);
    prop_kernel<1152, 4><<<N_NODES, 320, 0, stream>>>(row_ptr, col_s, w_s, u0, h1, h1);
    APtrs a4 = {{h1}};
    gemm_kernel<2, 1><<<GMT * nb, 256, 0, stream>>>(a4, Wt + 4 * wsl, b2, accb, u0,
                                                    N_NODES, NO, F, 576);
  }

  bf16* h2 = u0;  // h2 (ld 576)

  // layer 3: K=5, 576 -> 288
  wtrans_kernel<<<5 * 18 * 9, dim3(32, 8), 0, stream>>>(W3, Wt, 5, 576, 288);
  {
    const int F = 576, NO = 288, nb = 3;
    size_t wsl = (size_t)NO * F;
    prop_kernel<576, 2><<<N_NODES, 320, 0, stream>>>(row_ptr, col_s, w_s, h2, NB, u1);
    APtrs a01 = {{h2, u1}};
    gemm_kernel<0, 2><<<GMT * nb, 256, 0, stream>>>(a01, Wt, b3, accb, nullptr,
                                                    N_NODES, NO, F, 0);
    prop_kernel<576, 2><<<N_NODES, 320, 0, stream>>>(row_ptr, col_s, w_s, u1, h2, h2);
    prop_kernel<576, 2><<<N_NODES, 320, 0, stream>>>(row_ptr, col_s, w_s, h2, u1, u1);
    APtrs a23 = {{h2, u1}};
    gemm_kernel<1, 2><<<GMT * nb, 256, 0, stream>>>(a23, Wt + 2 * wsl, b3, accb, nullptr,
                                                    N_NODES, NO, F, 0);
    prop_kernel<576, 2><<<N_NODES, 320, 0, stream>>>(row_ptr, col_s, w_s, u1, h2, h2);
    APtrs a4 = {{h2}};
    gemm_kernel<3, 1><<<GMT * nb, 256, 0, stream>>>(a4, Wt + 4 * wsl, b3, accb, d_out,
                                                    N_NODES, NO, F, 0);
  }
}